// Round 2
// baseline (3432.491 us; speedup 1.0000x reference)
//
#include <hip/hip_runtime.h>
#include <math.h>

#define N_TOK 2048
#define DM    512
#define NW    16
#define WSZ   128
#define NH    8
#define DHD   64
#define FFD   2048
#define VOC   32000
#define NDEPTH 2

__device__ __forceinline__ float gelu_f(float v){
  return 0.5f*v*(1.0f+erff(v*0.70710678118654752440f));
}

// ---------------- prep kernels ----------------
__global__ void k_embed(const int* __restrict__ tok, const float* __restrict__ emb,
                        float* __restrict__ x){
  int idx = blockIdx.x*256 + threadIdx.x;
  int i = idx >> 9, d = idx & 511;
  x[idx] = emb[(size_t)tok[i]*DM + d];
}

__global__ void k_pool(const float* __restrict__ x, const float* __restrict__ gpos,
                       float* __restrict__ g){
  int idx = blockIdx.x*256 + threadIdx.x;  // NW*DM
  int w = idx >> 9, d = idx & 511;
  const float* p = x + (size_t)(w*WSZ)*DM + d;
  float s = 0.f;
  #pragma unroll 8
  for (int i=0;i<WSZ;i++) s += p[(size_t)i*DM];
  g[idx] = s*(1.f/WSZ) + gpos[idx];
}

__global__ void k_rotab(float* __restrict__ ct, float* __restrict__ st){
  int idx = blockIdx.x*256 + threadIdx.x; // N_TOK*32
  int i = idx >> 5, j = idx & 31;
  double inv = pow(10000.0, -(double)j/32.0);
  double a = (double)i*inv;
  ct[idx] = (float)cos(a);
  st[idx] = (float)sin(a);
}

__global__ void k_rope(float* __restrict__ q, float* __restrict__ k,
                       const float* __restrict__ ct, const float* __restrict__ st){
  int idx = blockIdx.x*256 + threadIdx.x; // N_TOK*NH*32
  int i = idx >> 8;
  int h = (idx >> 5) & 7;
  int j = idx & 31;
  float c = ct[i*32+j], s = st[i*32+j];
  size_t base = (size_t)i*DM + h*DHD + j;
  float q0=q[base], q1=q[base+32];
  q[base]    = q0*c - q1*s;
  q[base+32] = q1*c + q0*s;
  float k0=k[base], k1=k[base+32];
  k[base]    = k0*c - k1*s;
  k[base+32] = k1*c + k0*s;
}

__global__ __launch_bounds__(256) void k_ln(const float* __restrict__ in, float* __restrict__ out,
                     const float* __restrict__ w, const float* __restrict__ b){
  int r = blockIdx.x;
  const float2* p2 = reinterpret_cast<const float2*>(in + (size_t)r*DM);
  float2 v = p2[threadIdx.x];
  float s = v.x+v.y, ss = v.x*v.x + v.y*v.y;
  #pragma unroll
  for (int o=32;o;o>>=1){ s += __shfl_xor(s,o); ss += __shfl_xor(ss,o); }
  __shared__ float sm[4], sm2[4];
  int wv = threadIdx.x >> 6;
  if ((threadIdx.x & 63) == 0){ sm[wv]=s; sm2[wv]=ss; }
  __syncthreads();
  if (threadIdx.x == 0){
    float t=sm[0]+sm[1]+sm[2]+sm[3], t2=sm2[0]+sm2[1]+sm2[2]+sm2[3];
    float mu = t*(1.f/DM);
    float var = t2*(1.f/DM) - mu*mu;
    sm[0]=mu; sm2[0]=rsqrtf(var + 1e-5f);
  }
  __syncthreads();
  float mu = sm[0], rs = sm2[0];
  float2 wv2 = reinterpret_cast<const float2*>(w)[threadIdx.x];
  float2 bv2 = reinterpret_cast<const float2*>(b)[threadIdx.x];
  float2 o;
  o.x = (v.x-mu)*rs*wv2.x + bv2.x;
  o.y = (v.y-mu)*rs*wv2.y + bv2.y;
  reinterpret_cast<float2*>(out + (size_t)r*DM)[threadIdx.x] = o;
}

// ---------------- tiled SGEMM: C = [gelu](A@B + bias) [+ C] ----------------
// A row-major [M,K] lda, B row-major [K,N] ldb, C [M,N] ldc.
// Requires: M % BM == 0, N % BN == 0, K % BK == 0, BK*BN == 1024, BM/TM==16, BN/TN==16.
template<int BM,int BN,int BK,int TM,int TN,bool BIAS,bool RES,bool GELU>
__global__ __launch_bounds__(256) void k_gemm(
    const float* __restrict__ A, int lda,
    const float* __restrict__ B, int ldb,
    float* __restrict__ C, int ldc,
    const float* __restrict__ bias, int K)
{
  static_assert(BK*BN == 1024, "B tile loader assumes 1 float4/thread");
  constexpr int RS = TM/4, CS = TN/4;
  constexpr int RSTRIDE = BM/RS, CSTRIDE = BN/CS;
  __shared__ float As[BK][BM+4];
  __shared__ float Bs[BK][BN+4];
  const int tid = threadIdx.x;
  const int tx = tid & 15, ty = tid >> 4;
  const int bm0 = blockIdx.y*BM, bn0 = blockIdx.x*BN;
  const float* Ab = A + (size_t)bm0*lda;
  const float* Bb = B + bn0;
  float acc[TM][TN];
  #pragma unroll
  for (int i=0;i<TM;i++)
    #pragma unroll
    for (int j=0;j<TN;j++) acc[i][j]=0.f;

  constexpr int AE = BM*BK/256;
  const int br = tid / (BN/4), bc4 = tid % (BN/4);
  for (int kk=0; kk<K; kk+=BK){
    #pragma unroll
    for (int t=0;t<AE;t++){
      int e = tid + t*256;
      int r = e / BK, c = e % BK;
      As[c][r] = Ab[(size_t)r*lda + kk + c];
    }
    {
      const float4 v = *reinterpret_cast<const float4*>(&Bb[(size_t)(kk+br)*ldb + bc4*4]);
      *reinterpret_cast<float4*>(&Bs[br][bc4*4]) = v;
    }
    __syncthreads();
    #pragma unroll
    for (int k=0;k<BK;k++){
      float a[TM], b[TN];
      #pragma unroll
      for (int s=0;s<RS;s++){
        float4 v = *reinterpret_cast<const float4*>(&As[k][s*RSTRIDE + ty*4]);
        a[s*4+0]=v.x; a[s*4+1]=v.y; a[s*4+2]=v.z; a[s*4+3]=v.w;
      }
      #pragma unroll
      for (int s=0;s<CS;s++){
        float4 v = *reinterpret_cast<const float4*>(&Bs[k][s*CSTRIDE + tx*4]);
        b[s*4+0]=v.x; b[s*4+1]=v.y; b[s*4+2]=v.z; b[s*4+3]=v.w;
      }
      #pragma unroll
      for (int i=0;i<TM;i++)
        #pragma unroll
        for (int j=0;j<TN;j++)
          acc[i][j] = fmaf(a[i], b[j], acc[i][j]);
    }
    __syncthreads();
  }
  #pragma unroll
  for (int s=0;s<RS;s++)
  #pragma unroll
  for (int i=0;i<4;i++){
    const int row = bm0 + s*RSTRIDE + ty*4 + i;
    #pragma unroll
    for (int cs=0;cs<CS;cs++){
      const int col = bn0 + cs*CSTRIDE + tx*4;
      float4 v;
      v.x = acc[s*4+i][cs*4+0]; v.y = acc[s*4+i][cs*4+1];
      v.z = acc[s*4+i][cs*4+2]; v.w = acc[s*4+i][cs*4+3];
      if (BIAS){
        const float4 bv = *reinterpret_cast<const float4*>(&bias[col]);
        v.x+=bv.x; v.y+=bv.y; v.z+=bv.z; v.w+=bv.w;
      }
      if (GELU){ v.x=gelu_f(v.x); v.y=gelu_f(v.y); v.z=gelu_f(v.z); v.w=gelu_f(v.w); }
      float* cp = &C[(size_t)row*ldc + col];
      if (RES){
        const float4 o = *reinterpret_cast<const float4*>(cp);
        v.x+=o.x; v.y+=o.y; v.z+=o.z; v.w+=o.w;
      }
      *reinterpret_cast<float4*>(cp) = v;
    }
  }
}

// ---------------- small-M GEMM (M<=16, K % 512 == 0, N % 64 == 0) ----------------
template<bool BIAS,bool RES,bool GELU>
__global__ __launch_bounds__(256) void k_gemm_small(
    const float* __restrict__ A, int lda,
    const float* __restrict__ B, int ldb,
    float* __restrict__ C, int ldc,
    const float* __restrict__ bias, int M, int K)
{
  __shared__ float As[16*512];
  const int tid = threadIdx.x;
  const int col = blockIdx.x*64 + (tid & 63);
  const int rg = tid >> 6;
  float acc[4] = {0.f,0.f,0.f,0.f};
  for (int k0=0;k0<K;k0+=512){
    for (int e=tid;e<16*512;e+=256){
      int r = e >> 9, c = e & 511;
      As[e] = (r < M) ? A[(size_t)r*lda + k0 + c] : 0.f;
    }
    __syncthreads();
    for (int k=0;k<512;k++){
      float bv = B[(size_t)(k0+k)*ldb + col];
      #pragma unroll
      for (int i=0;i<4;i++) acc[i] = fmaf(As[(rg*4+i)*512 + k], bv, acc[i]);
    }
    __syncthreads();
  }
  #pragma unroll
  for (int i=0;i<4;i++){
    int r = rg*4+i;
    if (r < M){
      float v = acc[i];
      if (BIAS) v += bias[col];
      if (GELU) v = gelu_f(v);
      if (RES) v += C[(size_t)r*ldc + col];
      C[(size_t)r*ldc + col] = v;
    }
  }
}

// ---------------- global-token attention: 1 query vs 129 keys ----------------
// grid = NW*NH blocks, 64 threads. gq [16,512]; kvg [16,1024]; kvx [2048,1024].
__global__ __launch_bounds__(64) void k_gattn(
    const float* __restrict__ gq, const float* __restrict__ kvg,
    const float* __restrict__ kvx, float* __restrict__ out)
{
  const int w = blockIdx.x >> 3, h = blockIdx.x & 7;
  const int lane = threadIdx.x;
  __shared__ float qs[64];
  __shared__ float p[129];
  qs[lane] = gq[(size_t)w*DM + h*DHD + lane];
  __syncthreads();
  for (int c=0;c<3;c++){
    int j = c*64 + lane;
    if (j < 129){
      const float* kp = (j==0) ? &kvg[(size_t)w*1024 + h*DHD]
                               : &kvx[(size_t)(w*WSZ + j-1)*1024 + h*DHD];
      float s = 0.f;
      for (int d=0;d<64;d++) s = fmaf(qs[d], kp[d], s);
      p[j] = s*0.125f;
    }
  }
  __syncthreads();
  float mx = -3.4e38f;
  for (int j=lane;j<129;j+=64) mx = fmaxf(mx, p[j]);
  #pragma unroll
  for (int o=32;o;o>>=1) mx = fmaxf(mx, __shfl_xor(mx,o));
  float sum = 0.f;
  for (int j=lane;j<129;j+=64){ float e = expf(p[j]-mx); p[j]=e; sum+=e; }
  #pragma unroll
  for (int o=32;o;o>>=1) sum += __shfl_xor(sum,o);
  const float rs = 1.f/sum;
  __syncthreads();
  float o_ = 0.f;
  for (int j=0;j<129;j++){
    const float* vp = (j==0) ? &kvg[(size_t)w*1024 + 512 + h*DHD]
                             : &kvx[(size_t)(w*WSZ + j-1)*1024 + 512 + h*DHD];
    o_ = fmaf(p[j], vp[lane], o_);
  }
  out[(size_t)w*DM + h*DHD + lane] = o_*rs;
}

// ---------------- local windowed attention ----------------
// grid = NW*NH blocks, 256 threads (4 waves, 32 queries each).
// Keys: 15 global (visible j<w) + 256 local (prev window || cur window; visible m<=i+128).
// Local V == local K (faithful to reference closure bug). w==0 prev window = zeros (unmasked).
__global__ __launch_bounds__(256) void k_lattn(
    const float* __restrict__ q, const float* __restrict__ k,
    const float* __restrict__ gkv, float* __restrict__ out)
{
  __shared__ float Qs[WSZ][65];
  __shared__ float Ks[2*WSZ][65];
  __shared__ float Gk[15][65];
  __shared__ float Gv[15][65];
  __shared__ float pbuf[4][272];
  const int w = blockIdx.x >> 3, h = blockIdx.x & 7;
  const int tid = threadIdx.x;
  #pragma unroll
  for (int t=0;t<32;t++){
    int e = tid + t*256, r = e>>6, d = e&63;
    Qs[r][d] = q[(size_t)(w*WSZ + r)*DM + h*DHD + d];
  }
  #pragma unroll
  for (int t=0;t<64;t++){
    int e = tid + t*256, r = e>>6, d = e&63;
    float val;
    if (r < WSZ) val = (w==0) ? 0.f : k[(size_t)((w-1)*WSZ + r)*DM + h*DHD + d];
    else         val = k[(size_t)(w*WSZ + (r-WSZ))*DM + h*DHD + d];
    Ks[r][d] = val;
  }
  for (int e=tid;e<15*64;e+=256){
    int r = e>>6, d = e&63;
    Gk[r][d] = gkv[(size_t)r*1024 + h*DHD + d];
    Gv[r][d] = gkv[(size_t)r*1024 + 512 + h*DHD + d];
  }
  __syncthreads();
  const int wv = tid >> 6, lane = tid & 63;
  const int gl = (lane < 15) ? lane : 0;
  for (int t=0;t<32;t++){
    const int qi = wv*32 + t;
    float sl[4] = {0.f,0.f,0.f,0.f};
    float sg = 0.f;
    for (int d=0;d<64;d++){
      float qd = Qs[qi][d];
      #pragma unroll
      for (int c=0;c<4;c++) sl[c] = fmaf(qd, Ks[c*64+lane][d], sl[c]);
      sg = fmaf(qd, Gk[gl][d], sg);
    }
    float mx = -3.4e38f;
    #pragma unroll
    for (int c=0;c<4;c++){
      int m = c*64 + lane;
      sl[c] = (m <= qi + WSZ) ? sl[c]*0.125f : -3.4e38f;
      mx = fmaxf(mx, sl[c]);
    }
    sg = (lane < w) ? sg*0.125f : -3.4e38f;
    mx = fmaxf(mx, sg);
    #pragma unroll
    for (int o=32;o;o>>=1) mx = fmaxf(mx, __shfl_xor(mx, o));
    float sum = 0.f;
    #pragma unroll
    for (int c=0;c<4;c++){
      float e = (sl[c] > -1e37f) ? expf(sl[c]-mx) : 0.f;
      pbuf[wv][c*64+lane] = e;
      sum += e;
    }
    {
      float e = (sg > -1e37f) ? expf(sg-mx) : 0.f;
      if (lane < 15) pbuf[wv][256+lane] = e;
      sum += e;
    }
    #pragma unroll
    for (int o=32;o;o>>=1) sum += __shfl_xor(sum, o);
    const float rs = 1.f/sum;
    __syncthreads();
    float o_ = 0.f;
    #pragma unroll
    for (int j=0;j<15;j++) o_ = fmaf(pbuf[wv][256+j], Gv[j][lane], o_);
    const int mmax = qi + WSZ + 1;
    for (int m=0;m<mmax;m++) o_ = fmaf(pbuf[wv][m], Ks[m][lane], o_);
    out[(size_t)(w*WSZ + qi)*DM + h*DHD + lane] = o_*rs;
    __syncthreads();
  }
}

// ---------------- launch ----------------
extern "C" void kernel_launch(void* const* d_in, const int* in_sizes, int n_in,
                              void* d_out, int out_size, void* d_ws, size_t ws_size,
                              hipStream_t stream)
{
  (void)in_sizes; (void)n_in; (void)out_size; (void)ws_size;
  const int*   tokens   = (const int*)  d_in[0];
  const float* tok_emb  = (const float*)d_in[1];
  const float* gpos_emb = (const float*)d_in[2];
  const float* g_norm_w = (const float*)d_in[3];
  const float* g_norm_b = (const float*)d_in[4];
  const float* g_Wq     = (const float*)d_in[5];
  const float* g_Wkv    = (const float*)d_in[6];
  const float* g_Wo     = (const float*)d_in[7];
  const float* g_bo     = (const float*)d_in[8];
  const float* gffnw    = (const float*)d_in[9];
  const float* gffnb    = (const float*)d_in[10];
  const float* gff_W1   = (const float*)d_in[11];
  const float* gff_b1   = (const float*)d_in[12];
  const float* gff_W2   = (const float*)d_in[13];
  const float* gff_b2   = (const float*)d_in[14];
  const float* la_nw    = (const float*)d_in[15];
  const float* la_nb    = (const float*)d_in[16];
  const float* la_Wq    = (const float*)d_in[17];
  const float* la_Wkv   = (const float*)d_in[18];
  const float* la_Wo    = (const float*)d_in[19];
  const float* la_bo    = (const float*)d_in[20];
  const float* lff_nw   = (const float*)d_in[21];
  const float* lff_nb   = (const float*)d_in[22];
  const float* lff_W1   = (const float*)d_in[23];
  const float* lff_b1   = (const float*)d_in[24];
  const float* lff_W2   = (const float*)d_in[25];
  const float* lff_b2   = (const float*)d_in[26];
  const float* out_nw   = (const float*)d_in[27];
  const float* out_nb   = (const float*)d_in[28];
  const float* out_W    = (const float*)d_in[29];
  const float* out_b    = (const float*)d_in[30];
  float* O = (float*)d_out;

  float* ws = (float*)d_ws;
  const size_t ND = (size_t)N_TOK*DM;
  float* x    = ws;                       // [N, D] residual stream
  float* xn   = x + ND;                   // [N, D] LN scratch
  float* qb   = xn + ND;                  // [N, D] q  (also kv_x [N,1024] spanning qb..kb)
  float* kb   = qb + ND;                  // [N, D] k
  float* h1   = kb + ND;                  // [N, FF] ff hidden; ao aliases first N*D
  float* ao   = h1;
  float* g    = h1 + (size_t)N_TOK*FFD;   // [16, D]
  float* gn   = g  + NW*DM;
  float* gq   = gn + NW*DM;
  float* gao  = gq + NW*DM;
  float* gkvg = gao + NW*DM;              // [16, 1024]
  float* gh1  = gkvg + NW*1024;           // [16, FF]
  float* gkvl = gh1 + NW*FFD;             // [15, 1024]
  float* ct   = gkvl + 15*1024;           // [N, 32]
  float* st   = ct + (size_t)N_TOK*32;

  k_embed<<<N_TOK*DM/256, 256, 0, stream>>>(tokens, tok_emb, x);
  k_pool <<<NW*DM/256,   256, 0, stream>>>(x, gpos_emb, g);
  k_rotab<<<N_TOK*32/256,256, 0, stream>>>(ct, st);

  for (int l=0;l<NDEPTH;l++){
    // --- global-token transformer (weights shared across layers) ---
    k_ln<<<NW,256,0,stream>>>(g, gn, g_norm_w, g_norm_b);
    k_gemm_small<false,false,false><<<1024/64,256,0,stream>>>(gn,DM, g_Wkv,1024, gkvg,1024, nullptr, NW, DM);
    k_gemm_small<false,false,false><<<512/64, 256,0,stream>>>(gn,DM, g_Wq, 512,  gq, 512,  nullptr, NW, DM);
    k_gemm<64,64,16,4,4,false,false,false><<<dim3(1024/64, N_TOK/64),256,0,stream>>>(x,DM, g_Wkv,1024, qb,1024, nullptr, DM);
    k_gattn<<<NW*NH,64,0,stream>>>(gq, gkvg, qb, gao);
    k_gemm_small<true,true,false><<<512/64,256,0,stream>>>(gao,DM, g_Wo,DM, g,DM, g_bo, NW, DM);
    k_ln<<<NW,256,0,stream>>>(g, gn, gffnw, gffnb);
    k_gemm_small<true,false,true><<<FFD/64,256,0,stream>>>(gn,DM, gff_W1,FFD, gh1,FFD, gff_b1, NW, DM);
    k_gemm_small<true,true,false><<<512/64,256,0,stream>>>(gh1,FFD, gff_W2,DM, g,DM, gff_b2, NW, FFD);
    // --- local windowed attention ---
    k_gemm_small<false,false,false><<<1024/64,256,0,stream>>>(g,DM, la_Wkv + (size_t)l*DM*1024, 1024, gkvl,1024, nullptr, 15, DM);
    k_ln<<<N_TOK,256,0,stream>>>(x, xn, la_nw + l*DM, la_nb + l*DM);
    k_gemm<64,64,16,4,4,false,false,false><<<dim3(DM/64, N_TOK/64),256,0,stream>>>(xn,DM, la_Wq + (size_t)l*DM*DM, DM, qb,DM, nullptr, DM);
    // only the K half of la_Wkv is live (reference bug: windowed V == windowed K)
    k_gemm<64,64,16,4,4,false,false,false><<<dim3(DM/64, N_TOK/64),256,0,stream>>>(xn,DM, la_Wkv + (size_t)l*DM*1024, 1024, kb,DM, nullptr, DM);
    k_rope<<<N_TOK*NH*32/256,256,0,stream>>>(qb, kb, ct, st);
    k_lattn<<<NW*NH,256,0,stream>>>(qb, kb, gkvl, ao);
    k_gemm<64,64,16,4,4,true,true,false><<<dim3(DM/64, N_TOK/64),256,0,stream>>>(ao,DM, la_Wo + (size_t)l*DM*DM, DM, x,DM, la_bo + l*DM, DM);
    // --- local FFN ---
    k_ln<<<N_TOK,256,0,stream>>>(x, xn, lff_nw + l*DM, lff_nb + l*DM);
    k_gemm<128,128,8,8,8,true,false,true><<<dim3(FFD/128, N_TOK/128),256,0,stream>>>(xn,DM, lff_W1 + (size_t)l*DM*FFD, FFD, h1,FFD, lff_b1 + l*FFD, DM);
    k_gemm<64,64,16,4,4,true,true,false><<<dim3(DM/64, N_TOK/64),256,0,stream>>>(h1,FFD, lff_W2 + (size_t)l*FFD*DM, DM, x,DM, lff_b2 + l*DM, FFD);
  }
  // --- output head ---
  k_ln<<<N_TOK,256,0,stream>>>(x, xn, out_nw, out_nb);
  k_gemm<128,128,8,8,8,true,false,false><<<dim3(VOC/128, N_TOK/128),256,0,stream>>>(xn,DM, out_W,VOC, O,VOC, out_b, DM);
}

// Round 6
// 2315.735 us; speedup vs baseline: 1.4822x; 1.4822x over previous
//
#include <hip/hip_runtime.h>
#include <math.h>

#define N_TOK 2048
#define DM    512
#define NW    16
#define WSZ   128
#define NH    8
#define DHD   64
#define FFD   2048
#define VOC   32000
#define NDEPTH 2

typedef unsigned short u16;
typedef unsigned int   u32;
typedef __attribute__((ext_vector_type(8))) short bf16x8;  // 8 bf16 = 4 VGPR
typedef __attribute__((ext_vector_type(4))) float f32x4;

__device__ __forceinline__ float gelu_f(float v){
  return 0.5f*v*(1.0f+erff(v*0.70710678118654752440f));
}
__device__ __forceinline__ u16 f2bf(float f){   // RNE
  u32 u = __float_as_uint(f);
  u += 0x7fffu + ((u >> 16) & 1u);
  return (u16)(u >> 16);
}

// ---------------- prep kernels ----------------
__global__ void k_embed(const int* __restrict__ tok, const float* __restrict__ emb,
                        float* __restrict__ x, u16* __restrict__ xb){
  int idx = blockIdx.x*256 + threadIdx.x;
  int i = idx >> 9, d = idx & 511;
  float v = emb[(size_t)tok[i]*DM + d];
  x[idx] = v;
  xb[idx] = f2bf(v);
}

__global__ void k_pool(const float* __restrict__ x, const float* __restrict__ gpos,
                       float* __restrict__ g){
  int idx = blockIdx.x*256 + threadIdx.x;  // NW*DM
  int w = idx >> 9, d = idx & 511;
  const float* p = x + (size_t)(w*WSZ)*DM + d;
  float s = 0.f;
  #pragma unroll 8
  for (int i=0;i<WSZ;i++) s += p[(size_t)i*DM];
  g[idx] = s*(1.f/WSZ) + gpos[idx];
}

__global__ void k_rotab(float* __restrict__ ct, float* __restrict__ st){
  int idx = blockIdx.x*256 + threadIdx.x; // N_TOK*32
  int i = idx >> 5, j = idx & 31;
  double inv = pow(10000.0, -(double)j/32.0);
  double a = (double)i*inv;
  ct[idx] = (float)cos(a);
  st[idx] = (float)sin(a);
}

__global__ void k_rope(float* __restrict__ q, float* __restrict__ k,
                       const float* __restrict__ ct, const float* __restrict__ st){
  int idx = blockIdx.x*256 + threadIdx.x; // N_TOK*NH*32
  int i = idx >> 8;
  int h = (idx >> 5) & 7;
  int j = idx & 31;
  float c = ct[i*32+j], s = st[i*32+j];
  size_t base = (size_t)i*DM + h*DHD + j;
  float q0=q[base], q1=q[base+32];
  q[base]    = q0*c - q1*s;
  q[base+32] = q1*c + q0*s;
  float k0=k[base], k1=k[base+32];
  k[base]    = k0*c - k1*s;
  k[base+32] = k1*c + k0*s;
}

// LN over rows of length 512; BF=true writes packed bf16, else fp32.
template<bool BF>
__global__ __launch_bounds__(256) void k_ln(const float* __restrict__ in,
                     float* __restrict__ outf, u16* __restrict__ outb,
                     const float* __restrict__ w, const float* __restrict__ b){
  int r = blockIdx.x;
  const float2* p2 = reinterpret_cast<const float2*>(in + (size_t)r*DM);
  float2 v = p2[threadIdx.x];
  float s = v.x+v.y, ss = v.x*v.x + v.y*v.y;
  #pragma unroll
  for (int o=32;o;o>>=1){ s += __shfl_xor(s,o); ss += __shfl_xor(ss,o); }
  __shared__ float sm[4], sm2[4];
  int wv = threadIdx.x >> 6;
  if ((threadIdx.x & 63) == 0){ sm[wv]=s; sm2[wv]=ss; }
  __syncthreads();
  if (threadIdx.x == 0){
    float t=sm[0]+sm[1]+sm[2]+sm[3], t2=sm2[0]+sm2[1]+sm2[2]+sm2[3];
    float mu = t*(1.f/DM);
    float var = t2*(1.f/DM) - mu*mu;
    sm[0]=mu; sm2[0]=rsqrtf(var + 1e-5f);
  }
  __syncthreads();
  float mu = sm[0], rs = sm2[0];
  float2 wv2 = reinterpret_cast<const float2*>(w)[threadIdx.x];
  float2 bv2 = reinterpret_cast<const float2*>(b)[threadIdx.x];
  float ox = (v.x-mu)*rs*wv2.x + bv2.x;
  float oy = (v.y-mu)*rs*wv2.y + bv2.y;
  if (BF){
    reinterpret_cast<u32*>(outb)[(size_t)r*256 + threadIdx.x] =
        (u32)f2bf(ox) | ((u32)f2bf(oy) << 16);
  } else {
    float2 o; o.x = ox; o.y = oy;
    reinterpret_cast<float2*>(outf + (size_t)r*DM)[threadIdx.x] = o;
  }
}

// ---------------- weight transpose+convert: out[n][k] = bf16(in[k][c0+n]) ----------------
// grid (Nt/32, K/32), 256 threads.
__global__ __launch_bounds__(256) void k_wcvt(const float* __restrict__ in, int ldn, int c0,
                        u16* __restrict__ out, int K){
  __shared__ float t[32][33];
  const int tx = threadIdx.x & 31, ty = threadIdx.x >> 5;
  const int n0 = blockIdx.x*32, k0 = blockIdx.y*32;
  #pragma unroll
  for (int r = ty; r < 32; r += 8)
    t[r][tx] = in[(size_t)(k0+r)*ldn + c0 + n0 + tx];
  __syncthreads();
  #pragma unroll
  for (int r = ty; r < 32; r += 8)
    out[(size_t)(n0+r)*K + k0 + tx] = f2bf(t[tx][r]);
}

// ---------------- bf16 MFMA GEMM: C = [gelu](A@B + bias) [+ C] ----------------
// A bf16 [M][lda] row-major; Bt bf16 [N][K] row-major (B pre-transposed).
// 128x128 tile, BK=32, 4 waves each owning 64x64. fp32 accumulate.
// Requires M%128==0, N%128==0, K%32==0, lda%16==0, K%16==0.
template<bool BIAS,bool RES,bool GELU,bool SBF,bool SF32>
__global__ __launch_bounds__(256) void k_mgemm(
    const u16* __restrict__ A, int lda,
    const u16* __restrict__ Bt,
    float* __restrict__ C, int ldc,
    u16* __restrict__ Cb, int ldcb,
    const float* __restrict__ bias, int K)
{
  __shared__ __align__(16) u16 As[128*40];  // row stride 40 bf16 = 80 B (16B-aligned, 2-way banks)
  __shared__ __align__(16) u16 Bs[128*40];
  const int tid = threadIdx.x;
  const int bm0 = blockIdx.y*128, bn0 = blockIdx.x*128;
  const int lane = tid & 63, wid = tid >> 6;
  const int wr = wid >> 1, wc = wid & 1;
  const int r16 = lane & 15, ko = lane >> 4;
  const int srow = tid >> 1, koff = (tid & 1) * 16;
  const u16* Ap = A + (size_t)(bm0 + srow)*lda + koff;
  const u16* Bp = Bt + (size_t)(bn0 + srow)*K + koff;
  const u32 lwa = (u32)srow*40 + (u32)koff;

  f32x4 acc[4][4];
  #pragma unroll
  for (int m=0;m<4;m++)
    #pragma unroll
    for (int n=0;n<4;n++)
      acc[m][n] = (f32x4){0.f,0.f,0.f,0.f};

  for (int kk = 0; kk < K; kk += 32){
    const uint4 a0 = *reinterpret_cast<const uint4*>(Ap + kk);
    const uint4 a1 = *reinterpret_cast<const uint4*>(Ap + kk + 8);
    const uint4 b0 = *reinterpret_cast<const uint4*>(Bp + kk);
    const uint4 b1 = *reinterpret_cast<const uint4*>(Bp + kk + 8);
    *reinterpret_cast<uint4*>(&As[lwa])     = a0;
    *reinterpret_cast<uint4*>(&As[lwa + 8]) = a1;
    *reinterpret_cast<uint4*>(&Bs[lwa])     = b0;
    *reinterpret_cast<uint4*>(&Bs[lwa + 8]) = b1;
    __syncthreads();
    bf16x8 af[4], bfr[4];
    #pragma unroll
    for (int m=0;m<4;m++)
      af[m] = *reinterpret_cast<const bf16x8*>(&As[(u32)(wr*64 + m*16 + r16)*40 + (u32)ko*8]);
    #pragma unroll
    for (int n=0;n<4;n++)
      bfr[n] = *reinterpret_cast<const bf16x8*>(&Bs[(u32)(wc*64 + n*16 + r16)*40 + (u32)ko*8]);
    #pragma unroll
    for (int m=0;m<4;m++)
      #pragma unroll
      for (int n=0;n<4;n++)
        acc[m][n] = __builtin_amdgcn_mfma_f32_16x16x32_bf16(af[m], bfr[n], acc[m][n], 0, 0, 0);
    __syncthreads();
  }

  const int crow0 = bm0 + wr*64, ccol0 = bn0 + wc*64;
  #pragma unroll
  for (int m=0;m<4;m++){
    #pragma unroll
    for (int j=0;j<4;j++){
      const int row = crow0 + m*16 + ko*4 + j;
      #pragma unroll
      for (int n=0;n<4;n++){
        const int col = ccol0 + n*16 + r16;
        float v = acc[m][n][j];
        if (BIAS) v += bias[col];
        if (GELU) v = gelu_f(v);
        if (RES)  v += C[(size_t)row*ldc + col];
        if (SF32) C[(size_t)row*ldc + col] = v;
        if (SBF)  Cb[(size_t)row*ldcb + col] = f2bf(v);
      }
    }
  }
}

// ---------------- small-M GEMM (M<=16, K % 512 == 0, N % 64 == 0), fp32 ----------------
template<bool BIAS,bool RES,bool GELU>
__global__ __launch_bounds__(256) void k_gemm_small(
    const float* __restrict__ A, int lda,
    const float* __restrict__ B, int ldb,
    float* __restrict__ C, int ldc,
    const float* __restrict__ bias, int M, int K)
{
  __shared__ float As[16*512];
  const int tid = threadIdx.x;
  const int col = blockIdx.x*64 + (tid & 63);
  const int rg = tid >> 6;
  float acc[4] = {0.f,0.f,0.f,0.f};
  for (int k0=0;k0<K;k0+=512){
    for (int e=tid;e<16*512;e+=256){
      int r = e >> 9, c = e & 511;
      As[e] = (r < M) ? A[(size_t)r*lda + k0 + c] : 0.f;
    }
    __syncthreads();
    for (int k=0;k<512;k++){
      float bv = B[(size_t)(k0+k)*ldb + col];
      #pragma unroll
      for (int i=0;i<4;i++) acc[i] = fmaf(As[(rg*4+i)*512 + k], bv, acc[i]);
    }
    __syncthreads();
  }
  #pragma unroll
  for (int i=0;i<4;i++){
    int r = rg*4+i;
    if (r < M){
      float v = acc[i];
      if (BIAS) v += bias[col];
      if (GELU) v = gelu_f(v);
      if (RES) v += C[(size_t)r*ldc + col];
      C[(size_t)r*ldc + col] = v;
    }
  }
}

// ---------------- global-token attention: 1 query vs 129 keys ----------------
__global__ __launch_bounds__(64) void k_gattn(
    const float* __restrict__ gq, const float* __restrict__ kvg,
    const float* __restrict__ kvx, float* __restrict__ out)
{
  const int w = blockIdx.x >> 3, h = blockIdx.x & 7;
  const int lane = threadIdx.x;
  __shared__ float qs[64];
  __shared__ float p[129];
  qs[lane] = gq[(size_t)w*DM + h*DHD + lane];
  __syncthreads();
  for (int c=0;c<3;c++){
    int j = c*64 + lane;
    if (j < 129){
      const float* kp = (j==0) ? &kvg[(size_t)w*1024 + h*DHD]
                               : &kvx[(size_t)(w*WSZ + j-1)*1024 + h*DHD];
      float s = 0.f;
      for (int d=0;d<64;d++) s = fmaf(qs[d], kp[d], s);
      p[j] = s*0.125f;
    }
  }
  __syncthreads();
  float mx = -3.4e38f;
  for (int j=lane;j<129;j+=64) mx = fmaxf(mx, p[j]);
  #pragma unroll
  for (int o=32;o;o>>=1) mx = fmaxf(mx, __shfl_xor(mx,o));
  float sum = 0.f;
  for (int j=lane;j<129;j+=64){ float e = expf(p[j]-mx); p[j]=e; sum+=e; }
  #pragma unroll
  for (int o=32;o;o>>=1) sum += __shfl_xor(sum,o);
  const float rs = 1.f/sum;
  __syncthreads();
  float o_ = 0.f;
  for (int j=0;j<129;j++){
    const float* vp = (j==0) ? &kvg[(size_t)w*1024 + 512 + h*DHD]
                             : &kvx[(size_t)(w*WSZ + j-1)*1024 + 512 + h*DHD];
    o_ = fmaf(p[j], vp[lane], o_);
  }
  out[(size_t)w*DM + h*DHD + lane] = o_*rs;
}

// ---------------- local windowed attention (out -> bf16) ----------------
__global__ __launch_bounds__(256) void k_lattn(
    const float* __restrict__ q, const float* __restrict__ k,
    const float* __restrict__ gkv, u16* __restrict__ ob)
{
  __shared__ float Qs[WSZ][65];
  __shared__ float Ks[2*WSZ][65];
  __shared__ float Gk[15][65];
  __shared__ float Gv[15][65];
  __shared__ float pbuf[4][272];
  const int w = blockIdx.x >> 3, h = blockIdx.x & 7;
  const int tid = threadIdx.x;
  #pragma unroll
  for (int t=0;t<32;t++){
    int e = tid + t*256, r = e>>6, d = e&63;
    Qs[r][d] = q[(size_t)(w*WSZ + r)*DM + h*DHD + d];
  }
  #pragma unroll
  for (int t=0;t<64;t++){
    int e = tid + t*256, r = e>>6, d = e&63;
    float val;
    if (r < WSZ) val = (w==0) ? 0.f : k[(size_t)((w-1)*WSZ + r)*DM + h*DHD + d];
    else         val = k[(size_t)(w*WSZ + (r-WSZ))*DM + h*DHD + d];
    Ks[r][d] = val;
  }
  for (int e=tid;e<15*64;e+=256){
    int r = e>>6, d = e&63;
    Gk[r][d] = gkv[(size_t)r*1024 + h*DHD + d];
    Gv[r][d] = gkv[(size_t)r*1024 + 512 + h*DHD + d];
  }
  __syncthreads();
  const int wv = tid >> 6, lane = tid & 63;
  const int gl = (lane < 15) ? lane : 0;
  for (int t=0;t<32;t++){
    const int qi = wv*32 + t;
    float sl[4] = {0.f,0.f,0.f,0.f};
    float sg = 0.f;
    for (int d=0;d<64;d++){
      float qd = Qs[qi][d];
      #pragma unroll
      for (int c=0;c<4;c++) sl[c] = fmaf(qd, Ks[c*64+lane][d], sl[c]);
      sg = fmaf(qd, Gk[gl][d], sg);
    }
    float mx = -3.4e38f;
    #pragma unroll
    for (int c=0;c<4;c++){
      int m = c*64 + lane;
      sl[c] = (m <= qi + WSZ) ? sl[c]*0.125f : -3.4e38f;
      mx = fmaxf(mx, sl[c]);
    }
    sg = (lane < w) ? sg*0.125f : -3.4e38f;
    mx = fmaxf(mx, sg);
    #pragma unroll
    for (int o=32;o;o>>=1) mx = fmaxf(mx, __shfl_xor(mx, o));
    float sum = 0.f;
    #pragma unroll
    for (int c=0;c<4;c++){
      float e = (sl[c] > -1e37f) ? expf(sl[c]-mx) : 0.f;
      pbuf[wv][c*64+lane] = e;
      sum += e;
    }
    {
      float e = (sg > -1e37f) ? expf(sg-mx) : 0.f;
      if (lane < 15) pbuf[wv][256+lane] = e;
      sum += e;
    }
    #pragma unroll
    for (int o=32;o;o>>=1) sum += __shfl_xor(sum, o);
    const float rs = 1.f/sum;
    __syncthreads();
    float o_ = 0.f;
    #pragma unroll
    for (int j=0;j<15;j++) o_ = fmaf(pbuf[wv][256+j], Gv[j][lane], o_);
    const int mmax = qi + WSZ + 1;
    for (int m=0;m<mmax;m++) o_ = fmaf(pbuf[wv][m], Ks[m][lane], o_);
    ob[(size_t)(w*WSZ + qi)*DM + h*DHD + lane] = f2bf(o_*rs);
    __syncthreads();
  }
}

// ---------------- launch ----------------
extern "C" void kernel_launch(void* const* d_in, const int* in_sizes, int n_in,
                              void* d_out, int out_size, void* d_ws, size_t ws_size,
                              hipStream_t stream)
{
  (void)in_sizes; (void)n_in; (void)out_size; (void)ws_size;
  const int*   tokens   = (const int*)  d_in[0];
  const float* tok_emb  = (const float*)d_in[1];
  const float* gpos_emb = (const float*)d_in[2];
  const float* g_norm_w = (const float*)d_in[3];
  const float* g_norm_b = (const float*)d_in[4];
  const float* g_Wq     = (const float*)d_in[5];
  const float* g_Wkv    = (const float*)d_in[6];
  const float* g_Wo     = (const float*)d_in[7];
  const float* g_bo     = (const float*)d_in[8];
  const float* gffnw    = (const float*)d_in[9];
  const float* gffnb    = (const float*)d_in[10];
  const float* gff_W1   = (const float*)d_in[11];
  const float* gff_b1   = (const float*)d_in[12];
  const float* gff_W2   = (const float*)d_in[13];
  const float* gff_b2   = (const float*)d_in[14];
  const float* la_nw    = (const float*)d_in[15];
  const float* la_nb    = (const float*)d_in[16];
  const float* la_Wq    = (const float*)d_in[17];
  const float* la_Wkv   = (const float*)d_in[18];
  const float* la_Wo    = (const float*)d_in[19];
  const float* la_bo    = (const float*)d_in[20];
  const float* lff_nw   = (const float*)d_in[21];
  const float* lff_nb   = (const float*)d_in[22];
  const float* lff_W1   = (const float*)d_in[23];
  const float* lff_b1   = (const float*)d_in[24];
  const float* lff_W2   = (const float*)d_in[25];
  const float* lff_b2   = (const float*)d_in[26];
  const float* out_nw   = (const float*)d_in[27];
  const float* out_nb   = (const float*)d_in[28];
  const float* out_W    = (const float*)d_in[29];
  const float* out_b    = (const float*)d_in[30];
  float* O = (float*)d_out;

  float* ws = (float*)d_ws;
  float* x    = ws;                    // [2048,512] fp32 residual
  float* qb   = x + 1048576;           // [2048,512] q fp32 (qb..kb also = kvx [2048,1024])
  float* kb   = qb + 1048576;          // [2048,512] k fp32
  float* g    = kb + 1048576;          // [16,512]
  float* gn   = g + 8192;
  float* gq   = gn + 8192;
  float* gao  = gq + 8192;
  float* gkvg = gao + 8192;            // [16,1024]
  float* gh1  = gkvg + 16384;          // [16,2048]
  float* gkvl = gh1 + 32768;           // [15,1024]
  float* ct   = gkvl + 15360;          // [2048,32]
  float* st   = ct + 65536;
  u16* xb     = (u16*)(st + 65536);    // [2048,512] bf16 residual copy
  u16* xnb    = xb + 1048576;          // [2048,512] bf16 LN out
  u16* aob    = xnb + 1048576;         // [2048,512] bf16 attn out
  u16* h1b    = aob + 1048576;         // [2048,2048] bf16 FF hidden
  u16* Wt_voc = h1b + 4194304;         // [32000,512]
  u16* Wt_gkv = Wt_voc + 16384000;     // [1024,512]
  u16* Wt_ff1 = Wt_gkv + 524288;       // 2 x [2048,512]
  u16* Wt_ff2 = Wt_ff1 + 2097152;      // 2 x [512,2048]
  u16* Wt_q   = Wt_ff2 + 2097152;      // 2 x [512,512]
  u16* Wt_k   = Wt_q + 524288;         // 2 x [512,512] (K-half of la_Wkv)
  u16* Wt_o   = Wt_k + 524288;         // 2 x [512,512]

  // ---- weight transpose+convert pre-pass (inputs only; graph-safe) ----
  k_wcvt<<<dim3(VOC/32, 16), 256, 0, stream>>>(out_W, VOC, 0, Wt_voc, DM);
  k_wcvt<<<dim3(32, 16),     256, 0, stream>>>(g_Wkv, 1024, 0, Wt_gkv, DM);
  for (int l=0;l<NDEPTH;l++){
    k_wcvt<<<dim3(64, 16), 256, 0, stream>>>(lff_W1 + (size_t)l*DM*FFD, FFD, 0, Wt_ff1 + (size_t)l*1048576, DM);
    k_wcvt<<<dim3(16, 64), 256, 0, stream>>>(lff_W2 + (size_t)l*FFD*DM, DM, 0, Wt_ff2 + (size_t)l*1048576, FFD);
    k_wcvt<<<dim3(16, 16), 256, 0, stream>>>(la_Wq  + (size_t)l*DM*DM, DM, 0, Wt_q + (size_t)l*262144, DM);
    k_wcvt<<<dim3(16, 16), 256, 0, stream>>>(la_Wkv + (size_t)l*DM*1024, 1024, 0, Wt_k + (size_t)l*262144, DM);
    k_wcvt<<<dim3(16, 16), 256, 0, stream>>>(la_Wo  + (size_t)l*DM*DM, DM, 0, Wt_o + (size_t)l*262144, DM);
  }

  k_embed<<<N_TOK*DM/256, 256, 0, stream>>>(tokens, tok_emb, x, xb);
  k_pool <<<NW*DM/256,   256, 0, stream>>>(x, gpos_emb, g);
  k_rotab<<<N_TOK*32/256,256, 0, stream>>>(ct, st);

  for (int l=0;l<NDEPTH;l++){
    // --- global-token transformer (weights shared across layers, fp32 path) ---
    k_ln<false><<<NW,256,0,stream>>>(g, gn, nullptr, g_norm_w, g_norm_b);
    k_gemm_small<false,false,false><<<1024/64,256,0,stream>>>(gn,DM, g_Wkv,1024, gkvg,1024, nullptr, NW, DM);
    k_gemm_small<false,false,false><<<512/64, 256,0,stream>>>(gn,DM, g_Wq, 512,  gq, 512,  nullptr, NW, DM);
    // kvx = x @ g_Wkv (bf16 MFMA)
    k_mgemm<false,false,false,false,true><<<dim3(8,16),256,0,stream>>>(xb, DM, Wt_gkv, qb, 1024, nullptr, 0, nullptr, DM);
    k_gattn<<<NW*NH,64,0,stream>>>(gq, gkvg, qb, gao);
    k_gemm_small<true,true,false><<<512/64,256,0,stream>>>(gao,DM, g_Wo,DM, g,DM, g_bo, NW, DM);
    k_ln<false><<<NW,256,0,stream>>>(g, gn, nullptr, gffnw, gffnb);
    k_gemm_small<true,false,true><<<FFD/64,256,0,stream>>>(gn,DM, gff_W1,FFD, gh1,FFD, gff_b1, NW, DM);
    k_gemm_small<true,true,false><<<512/64,256,0,stream>>>(gh1,FFD, gff_W2,DM, g,DM, gff_b2, NW, FFD);
    // --- local windowed attention ---
    k_gemm_small<false,false,false><<<1024/64,256,0,stream>>>(g,DM, la_Wkv + (size_t)l*DM*1024, 1024, gkvl,1024, nullptr, 15, DM);
    k_ln<true><<<N_TOK,256,0,stream>>>(x, nullptr, xnb, la_nw + l*DM, la_nb + l*DM);
    k_mgemm<false,false,false,false,true><<<dim3(4,16),256,0,stream>>>(xnb, DM, Wt_q + (size_t)l*262144, qb, DM, nullptr, 0, nullptr, DM);
    // only the K half of la_Wkv is live (reference bug: windowed V == windowed K)
    k_mgemm<false,false,false,false,true><<<dim3(4,16),256,0,stream>>>(xnb, DM, Wt_k + (size_t)l*262144, kb, DM, nullptr, 0, nullptr, DM);
    k_rope<<<N_TOK*NH*32/256,256,0,stream>>>(qb, kb, ct, st);
    k_lattn<<<NW*NH,256,0,stream>>>(qb, kb, gkvl, aob);
    k_mgemm<true,true,false,true,true><<<dim3(4,16),256,0,stream>>>(aob, DM, Wt_o + (size_t)l*262144, x, DM, xb, DM, la_bo + l*DM, DM);
    // --- local FFN ---
    k_ln<true><<<N_TOK,256,0,stream>>>(x, nullptr, xnb, lff_nw + l*DM, lff_nb + l*DM);
    k_mgemm<true,false,true,true,false><<<dim3(16,16),256,0,stream>>>(xnb, DM, Wt_ff1 + (size_t)l*1048576, nullptr, 0, h1b, FFD, lff_b1 + l*FFD, DM);
    k_mgemm<true,true,false,true,true><<<dim3(4,16),256,0,stream>>>(h1b, FFD, Wt_ff2 + (size_t)l*1048576, x, DM, xb, DM, lff_b2 + l*DM, FFD);
  }
  // --- output head (bf16 MFMA) ---
  k_ln<true><<<N_TOK,256,0,stream>>>(x, nullptr, xnb, out_nw, out_nb);
  k_mgemm<true,false,false,false,true><<<dim3(VOC/128,16),256,0,stream>>>(xnb, DM, Wt_voc, O, VOC, nullptr, 0, out_b, DM);
}

// Round 8
// 1587.389 us; speedup vs baseline: 2.1623x; 1.4588x over previous
//
#include <hip/hip_runtime.h>
#include <math.h>

#define N_TOK 2048
#define DM    512
#define NW    16
#define WSZ   128
#define NH    8
#define DHD   64
#define FFD   2048
#define VOC   32000
#define NDEPTH 2

typedef unsigned short u16;
typedef unsigned int   u32;
typedef __attribute__((ext_vector_type(8))) short bf16x8;  // 8 bf16 = 4 VGPR
typedef __attribute__((ext_vector_type(4))) float f32x4;

__device__ __forceinline__ float gelu_f(float v){
  return 0.5f*v*(1.0f+erff(v*0.70710678118654752440f));
}
__device__ __forceinline__ u16 f2bf(float f){   // RNE
  u32 u = __float_as_uint(f);
  u += 0x7fffu + ((u >> 16) & 1u);
  return (u16)(u >> 16);
}

// ---------------- prep kernels ----------------
__global__ void k_embed(const int* __restrict__ tok, const float* __restrict__ emb,
                        float* __restrict__ x, u16* __restrict__ xb){
  int idx = blockIdx.x*256 + threadIdx.x;
  int i = idx >> 9, d = idx & 511;
  float v = emb[(size_t)tok[i]*DM + d];
  x[idx] = v;
  xb[idx] = f2bf(v);
}

__global__ void k_pool(const float* __restrict__ x, const float* __restrict__ gpos,
                       float* __restrict__ g){
  int idx = blockIdx.x*256 + threadIdx.x;  // NW*DM
  int w = idx >> 9, d = idx & 511;
  const float* p = x + (size_t)(w*WSZ)*DM + d;
  float s = 0.f;
  #pragma unroll 8
  for (int i=0;i<WSZ;i++) s += p[(size_t)i*DM];
  g[idx] = s*(1.f/WSZ) + gpos[idx];
}

__global__ void k_rotab(float* __restrict__ ct, float* __restrict__ st){
  int idx = blockIdx.x*256 + threadIdx.x; // N_TOK*32
  int i = idx >> 5, j = idx & 31;
  double inv = pow(10000.0, -(double)j/32.0);
  double a = (double)i*inv;
  ct[idx] = (float)cos(a);
  st[idx] = (float)sin(a);
}

__global__ void k_rope(float* __restrict__ q, float* __restrict__ k,
                       const float* __restrict__ ct, const float* __restrict__ st){
  int idx = blockIdx.x*256 + threadIdx.x; // N_TOK*NH*32
  int i = idx >> 8;
  int h = (idx >> 5) & 7;
  int j = idx & 31;
  float c = ct[i*32+j], s = st[i*32+j];
  size_t base = (size_t)i*DM + h*DHD + j;
  float q0=q[base], q1=q[base+32];
  q[base]    = q0*c - q1*s;
  q[base+32] = q1*c + q0*s;
  float k0=k[base], k1=k[base+32];
  k[base]    = k0*c - k1*s;
  k[base+32] = k1*c + k0*s;
}

// LN over rows of length 512; BF=true writes packed bf16, else fp32.
template<bool BF>
__global__ __launch_bounds__(256) void k_ln(const float* __restrict__ in,
                     float* __restrict__ outf, u16* __restrict__ outb,
                     const float* __restrict__ w, const float* __restrict__ b){
  int r = blockIdx.x;
  const float2* p2 = reinterpret_cast<const float2*>(in + (size_t)r*DM);
  float2 v = p2[threadIdx.x];
  float s = v.x+v.y, ss = v.x*v.x + v.y*v.y;
  #pragma unroll
  for (int o=32;o;o>>=1){ s += __shfl_xor(s,o); ss += __shfl_xor(ss,o); }
  __shared__ float sm[4], sm2[4];
  int wv = threadIdx.x >> 6;
  if ((threadIdx.x & 63) == 0){ sm[wv]=s; sm2[wv]=ss; }
  __syncthreads();
  if (threadIdx.x == 0){
    float t=sm[0]+sm[1]+sm[2]+sm[3], t2=sm2[0]+sm2[1]+sm2[2]+sm2[3];
    float mu = t*(1.f/DM);
    float var = t2*(1.f/DM) - mu*mu;
    sm[0]=mu; sm2[0]=rsqrtf(var + 1e-5f);
  }
  __syncthreads();
  float mu = sm[0], rs = sm2[0];
  float2 wv2 = reinterpret_cast<const float2*>(w)[threadIdx.x];
  float2 bv2 = reinterpret_cast<const float2*>(b)[threadIdx.x];
  float ox = (v.x-mu)*rs*wv2.x + bv2.x;
  float oy = (v.y-mu)*rs*wv2.y + bv2.y;
  if (BF){
    reinterpret_cast<u32*>(outb)[(size_t)r*256 + threadIdx.x] =
        (u32)f2bf(ox) | ((u32)f2bf(oy) << 16);
  } else {
    float2 o; o.x = ox; o.y = oy;
    reinterpret_cast<float2*>(outf + (size_t)r*DM)[threadIdx.x] = o;
  }
}

// ---------------- weight transpose+convert: out[n][k] = bf16(in[k][c0+n]) ----------------
// grid (Nt/32, K/32), 256 threads.
__global__ __launch_bounds__(256) void k_wcvt(const float* __restrict__ in, int ldn, int c0,
                        u16* __restrict__ out, int K){
  __shared__ float t[32][33];
  const int tx = threadIdx.x & 31, ty = threadIdx.x >> 5;
  const int n0 = blockIdx.x*32, k0 = blockIdx.y*32;
  #pragma unroll
  for (int r = ty; r < 32; r += 8)
    t[r][tx] = in[(size_t)(k0+r)*ldn + c0 + n0 + tx];
  __syncthreads();
  #pragma unroll
  for (int r = ty; r < 32; r += 8)
    out[(size_t)(n0+r)*K + k0 + tx] = f2bf(t[tx][r]);
}

// ---------------- bf16 MFMA GEMM: C = [gelu](A@B + bias) [+ C] ----------------
// A bf16 [M][lda] row-major; Bt bf16 [N][K] row-major (B pre-transposed).
// 128x128 tile, BK=32, 4 waves each owning 64x64. fp32 accumulate.
template<bool BIAS,bool RES,bool GELU,bool SBF,bool SF32>
__global__ __launch_bounds__(256) void k_mgemm(
    const u16* __restrict__ A, int lda,
    const u16* __restrict__ Bt,
    float* __restrict__ C, int ldc,
    u16* __restrict__ Cb, int ldcb,
    const float* __restrict__ bias, int K)
{
  __shared__ __align__(16) u16 As[128*40];  // row stride 40 bf16 = 80 B (16B-aligned, 2-way banks)
  __shared__ __align__(16) u16 Bs[128*40];
  const int tid = threadIdx.x;
  const int bm0 = blockIdx.y*128, bn0 = blockIdx.x*128;
  const int lane = tid & 63, wid = tid >> 6;
  const int wr = wid >> 1, wc = wid & 1;
  const int r16 = lane & 15, ko = lane >> 4;
  const int srow = tid >> 1, koff = (tid & 1) * 16;
  const u16* Ap = A + (size_t)(bm0 + srow)*lda + koff;
  const u16* Bp = Bt + (size_t)(bn0 + srow)*K + koff;
  const u32 lwa = (u32)srow*40 + (u32)koff;

  f32x4 acc[4][4];
  #pragma unroll
  for (int m=0;m<4;m++)
    #pragma unroll
    for (int n=0;n<4;n++)
      acc[m][n] = (f32x4){0.f,0.f,0.f,0.f};

  for (int kk = 0; kk < K; kk += 32){
    const uint4 a0 = *reinterpret_cast<const uint4*>(Ap + kk);
    const uint4 a1 = *reinterpret_cast<const uint4*>(Ap + kk + 8);
    const uint4 b0 = *reinterpret_cast<const uint4*>(Bp + kk);
    const uint4 b1 = *reinterpret_cast<const uint4*>(Bp + kk + 8);
    *reinterpret_cast<uint4*>(&As[lwa])     = a0;
    *reinterpret_cast<uint4*>(&As[lwa + 8]) = a1;
    *reinterpret_cast<uint4*>(&Bs[lwa])     = b0;
    *reinterpret_cast<uint4*>(&Bs[lwa + 8]) = b1;
    __syncthreads();
    bf16x8 af[4], bfr[4];
    #pragma unroll
    for (int m=0;m<4;m++)
      af[m] = *reinterpret_cast<const bf16x8*>(&As[(u32)(wr*64 + m*16 + r16)*40 + (u32)ko*8]);
    #pragma unroll
    for (int n=0;n<4;n++)
      bfr[n] = *reinterpret_cast<const bf16x8*>(&Bs[(u32)(wc*64 + n*16 + r16)*40 + (u32)ko*8]);
    #pragma unroll
    for (int m=0;m<4;m++)
      #pragma unroll
      for (int n=0;n<4;n++)
        acc[m][n] = __builtin_amdgcn_mfma_f32_16x16x32_bf16(af[m], bfr[n], acc[m][n], 0, 0, 0);
    __syncthreads();
  }

  const int crow0 = bm0 + wr*64, ccol0 = bn0 + wc*64;
  #pragma unroll
  for (int m=0;m<4;m++){
    #pragma unroll
    for (int j=0;j<4;j++){
      const int row = crow0 + m*16 + ko*4 + j;
      #pragma unroll
      for (int n=0;n<4;n++){
        const int col = ccol0 + n*16 + r16;
        float v = acc[m][n][j];
        if (BIAS) v += bias[col];
        if (GELU) v = gelu_f(v);
        if (RES)  v += C[(size_t)row*ldc + col];
        if (SF32) C[(size_t)row*ldc + col] = v;
        if (SBF)  Cb[(size_t)row*ldcb + col] = f2bf(v);
      }
    }
  }
}

// ---------------- small-M GEMM, split-K stage 1 ----------------
// P[s][16][N] partial = A[0:M][s*64:(s+1)*64] @ B[s*64:(s+1)*64][n-chunk]
// grid (N/256, K/64), 256 threads. A fp32 [M][lda] (M<=16), B fp32 [K][ldb].
// Wave w = row-group rg: all 64 lanes read the SAME A element (LDS broadcast),
// B loads are 64 lanes x float4 = 1KB fully coalesced.
__global__ __launch_bounds__(256) void k_psum(
    const float* __restrict__ A, int lda,
    const float* __restrict__ B, int ldb,
    float* __restrict__ P, int N, int M)
{
  __shared__ __align__(16) float As[16][68];   // 272B row stride: 16B-aligned
  const int tid = threadIdx.x;
  const int cg = tid & 63, rg = tid >> 6;
  const int n0 = blockIdx.x*256 + cg*4;
  const int k0 = blockIdx.y*64;
  for (int e = tid; e < 16*64; e += 256){
    int r = e >> 6, c = e & 63;
    As[r][c] = (r < M) ? A[(size_t)r*lda + k0 + c] : 0.f;
  }
  __syncthreads();
  float4 acc0 = {0.f,0.f,0.f,0.f}, acc1 = acc0, acc2 = acc0, acc3 = acc0;
  const float* Bp = B + (size_t)k0*ldb + n0;
  #pragma unroll 4
  for (int k4 = 0; k4 < 64; k4 += 4){
    float a0[4], a1[4], a2[4], a3[4];
    *reinterpret_cast<float4*>(a0) = *reinterpret_cast<const float4*>(&As[rg*4+0][k4]);
    *reinterpret_cast<float4*>(a1) = *reinterpret_cast<const float4*>(&As[rg*4+1][k4]);
    *reinterpret_cast<float4*>(a2) = *reinterpret_cast<const float4*>(&As[rg*4+2][k4]);
    *reinterpret_cast<float4*>(a3) = *reinterpret_cast<const float4*>(&As[rg*4+3][k4]);
    #pragma unroll
    for (int j = 0; j < 4; j++){
      const float4 bv = *reinterpret_cast<const float4*>(Bp + (size_t)(k4+j)*ldb);
      acc0.x = fmaf(a0[j], bv.x, acc0.x); acc0.y = fmaf(a0[j], bv.y, acc0.y);
      acc0.z = fmaf(a0[j], bv.z, acc0.z); acc0.w = fmaf(a0[j], bv.w, acc0.w);
      acc1.x = fmaf(a1[j], bv.x, acc1.x); acc1.y = fmaf(a1[j], bv.y, acc1.y);
      acc1.z = fmaf(a1[j], bv.z, acc1.z); acc1.w = fmaf(a1[j], bv.w, acc1.w);
      acc2.x = fmaf(a2[j], bv.x, acc2.x); acc2.y = fmaf(a2[j], bv.y, acc2.y);
      acc2.z = fmaf(a2[j], bv.z, acc2.z); acc2.w = fmaf(a2[j], bv.w, acc2.w);
      acc3.x = fmaf(a3[j], bv.x, acc3.x); acc3.y = fmaf(a3[j], bv.y, acc3.y);
      acc3.z = fmaf(a3[j], bv.z, acc3.z); acc3.w = fmaf(a3[j], bv.w, acc3.w);
    }
  }
  float* Pp = P + ((size_t)blockIdx.y*16 + rg*4)*N + n0;
  *reinterpret_cast<float4*>(Pp)       = acc0;
  *reinterpret_cast<float4*>(Pp + N)   = acc1;
  *reinterpret_cast<float4*>(Pp + 2*N) = acc2;
  *reinterpret_cast<float4*>(Pp + 3*N) = acc3;
}

// ---------------- small-M GEMM, split-K stage 2 (reduce + epilogue) ----------------
// grid (16*N/256). C[r][n] = [gelu](sum_s P[s][r][n] + bias) [+ C]
template<bool BIAS,bool RES,bool GELU>
__global__ __launch_bounds__(256) void k_red(
    const float* __restrict__ P, int N, int S, int M,
    float* __restrict__ C, int ldc, const float* __restrict__ bias)
{
  int idx = blockIdx.x*256 + threadIdx.x;
  int r = idx / N, n = idx - r*N;
  if (r >= M) return;
  float v = 0.f;
  for (int s = 0; s < S; s++) v += P[((size_t)s*16 + r)*N + n];
  if (BIAS) v += bias[n];
  if (GELU) v = gelu_f(v);
  if (RES)  v += C[(size_t)r*ldc + n];
  C[(size_t)r*ldc + n] = v;
}

// ---------------- global-token attention: 1 query vs 129 keys ----------------
__global__ __launch_bounds__(64) void k_gattn(
    const float* __restrict__ gq, const float* __restrict__ kvg,
    const float* __restrict__ kvx, float* __restrict__ out)
{
  const int w = blockIdx.x >> 3, h = blockIdx.x & 7;
  const int lane = threadIdx.x;
  __shared__ float qs[64];
  __shared__ float p[129];
  qs[lane] = gq[(size_t)w*DM + h*DHD + lane];
  __syncthreads();
  for (int c=0;c<3;c++){
    int j = c*64 + lane;
    if (j < 129){
      const float* kp = (j==0) ? &kvg[(size_t)w*1024 + h*DHD]
                               : &kvx[(size_t)(w*WSZ + j-1)*1024 + h*DHD];
      float s = 0.f;
      for (int d=0;d<64;d++) s = fmaf(qs[d], kp[d], s);
      p[j] = s*0.125f;
    }
  }
  __syncthreads();
  float mx = -3.4e38f;
  for (int j=lane;j<129;j+=64) mx = fmaxf(mx, p[j]);
  #pragma unroll
  for (int o=32;o;o>>=1) mx = fmaxf(mx, __shfl_xor(mx,o));
  float sum = 0.f;
  for (int j=lane;j<129;j+=64){ float e = expf(p[j]-mx); p[j]=e; sum+=e; }
  #pragma unroll
  for (int o=32;o;o>>=1) sum += __shfl_xor(sum,o);
  const float rs = 1.f/sum;
  __syncthreads();
  float o_ = 0.f;
  for (int j=0;j<129;j++){
    const float* vp = (j==0) ? &kvg[(size_t)w*1024 + 512 + h*DHD]
                             : &kvx[(size_t)(w*WSZ + j-1)*1024 + 512 + h*DHD];
    o_ = fmaf(p[j], vp[lane], o_);
  }
  out[(size_t)w*DM + h*DHD + lane] = o_*rs;
}

// ---------------- local windowed attention (out -> bf16) ----------------
__global__ __launch_bounds__(256) void k_lattn(
    const float* __restrict__ q, const float* __restrict__ k,
    const float* __restrict__ gkv, u16* __restrict__ ob)
{
  __shared__ float Qs[WSZ][65];
  __shared__ float Ks[2*WSZ][65];
  __shared__ float Gk[15][65];
  __shared__ float Gv[15][65];
  __shared__ float pbuf[4][272];
  const int w = blockIdx.x >> 3, h = blockIdx.x & 7;
  const int tid = threadIdx.x;
  #pragma unroll
  for (int t=0;t<32;t++){
    int e = tid + t*256, r = e>>6, d = e&63;
    Qs[r][d] = q[(size_t)(w*WSZ + r)*DM + h*DHD + d];
  }
  #pragma unroll
  for (int t=0;t<64;t++){
    int e = tid + t*256, r = e>>6, d = e&63;
    float val;
    if (r < WSZ) val = (w==0) ? 0.f : k[(size_t)((w-1)*WSZ + r)*DM + h*DHD + d];
    else         val = k[(size_t)(w*WSZ + (r-WSZ))*DM + h*DHD + d];
    Ks[r][d] = val;
  }
  for (int e=tid;e<15*64;e+=256){
    int r = e>>6, d = e&63;
    Gk[r][d] = gkv[(size_t)r*1024 + h*DHD + d];
    Gv[r][d] = gkv[(size_t)r*1024 + 512 + h*DHD + d];
  }
  __syncthreads();
  const int wv = tid >> 6, lane = tid & 63;
  const int gl = (lane < 15) ? lane : 0;
  for (int t=0;t<32;t++){
    const int qi = wv*32 + t;
    float sl[4] = {0.f,0.f,0.f,0.f};
    float sg = 0.f;
    for (int d=0;d<64;d++){
      float qd = Qs[qi][d];
      #pragma unroll
      for (int c=0;c<4;c++) sl[c] = fmaf(qd, Ks[c*64+lane][d], sl[c]);
      sg = fmaf(qd, Gk[gl][d], sg);
    }
    float mx = -3.4e38f;
    #pragma unroll
    for (int c=0;c<4;c++){
      int m = c*64 + lane;
      sl[c] = (m <= qi + WSZ) ? sl[c]*0.125f : -3.4e38f;
      mx = fmaxf(mx, sl[c]);
    }
    sg = (lane < w) ? sg*0.125f : -3.4e38f;
    mx = fmaxf(mx, sg);
    #pragma unroll
    for (int o=32;o;o>>=1) mx = fmaxf(mx, __shfl_xor(mx, o));
    float sum = 0.f;
    #pragma unroll
    for (int c=0;c<4;c++){
      float e = (sl[c] > -1e37f) ? expf(sl[c]-mx) : 0.f;
      pbuf[wv][c*64+lane] = e;
      sum += e;
    }
    {
      float e = (sg > -1e37f) ? expf(sg-mx) : 0.f;
      if (lane < 15) pbuf[wv][256+lane] = e;
      sum += e;
    }
    #pragma unroll
    for (int o=32;o;o>>=1) sum += __shfl_xor(sum, o);
    const float rs = 1.f/sum;
    __syncthreads();
    float o_ = 0.f;
    #pragma unroll
    for (int j=0;j<15;j++) o_ = fmaf(pbuf[wv][256+j], Gv[j][lane], o_);
    const int mmax = qi + WSZ + 1;
    for (int m=0;m<mmax;m++) o_ = fmaf(pbuf[wv][m], Ks[m][lane], o_);
    ob[(size_t)(w*WSZ + qi)*DM + h*DHD + lane] = f2bf(o_*rs);
    __syncthreads();
  }
}

// ---------------- launch ----------------
extern "C" void kernel_launch(void* const* d_in, const int* in_sizes, int n_in,
                              void* d_out, int out_size, void* d_ws, size_t ws_size,
                              hipStream_t stream)
{
  (void)in_sizes; (void)n_in; (void)out_size; (void)ws_size;
  const int*   tokens   = (const int*)  d_in[0];
  const float* tok_emb  = (const float*)d_in[1];
  const float* gpos_emb = (const float*)d_in[2];
  const float* g_norm_w = (const float*)d_in[3];
  const float* g_norm_b = (const float*)d_in[4];
  const float* g_Wq     = (const float*)d_in[5];
  const float* g_Wkv    = (const float*)d_in[6];
  const float* g_Wo     = (const float*)d_in[7];
  const float* g_bo     = (const float*)d_in[8];
  const float* gffnw    = (const float*)d_in[9];
  const float* gffnb    = (const float*)d_in[10];
  const float* gff_W1   = (const float*)d_in[11];
  const float* gff_b1   = (const float*)d_in[12];
  const float* gff_W2   = (const float*)d_in[13];
  const float* gff_b2   = (const float*)d_in[14];
  const float* la_nw    = (const float*)d_in[15];
  const float* la_nb    = (const float*)d_in[16];
  const float* la_Wq    = (const float*)d_in[17];
  const float* la_Wkv   = (const float*)d_in[18];
  const float* la_Wo    = (const float*)d_in[19];
  const float* la_bo    = (const float*)d_in[20];
  const float* lff_nw   = (const float*)d_in[21];
  const float* lff_nb   = (const float*)d_in[22];
  const float* lff_W1   = (const float*)d_in[23];
  const float* lff_b1   = (const float*)d_in[24];
  const float* lff_W2   = (const float*)d_in[25];
  const float* lff_b2   = (const float*)d_in[26];
  const float* out_nw   = (const float*)d_in[27];
  const float* out_nb   = (const float*)d_in[28];
  const float* out_W    = (const float*)d_in[29];
  const float* out_b    = (const float*)d_in[30];
  float* O = (float*)d_out;

  float* ws = (float*)d_ws;
  float* x    = ws;                    // [2048,512] fp32 residual
  float* qb   = x + 1048576;           // [2048,512] q fp32 (qb..kb also = kvx [2048,1024])
  float* kb   = qb + 1048576;          // [2048,512] k fp32
  float* g    = kb + 1048576;          // [16,512]
  float* gn   = g + 8192;
  float* gq   = gn + 8192;
  float* gao  = gq + 8192;
  float* gkvg = gao + 8192;            // [16,1024]
  float* gh1  = gkvg + 16384;          // [16,2048]
  float* gkvl = gh1 + 32768;           // [15,1024]
  float* ct   = gkvl + 15360;          // [2048,32]
  float* st   = ct + 65536;
  u16* xb     = (u16*)(st + 65536);    // [2048,512] bf16 residual copy
  u16* xnb    = xb + 1048576;          // [2048,512] bf16 LN out
  u16* aob    = xnb + 1048576;         // [2048,512] bf16 attn out
  u16* h1b    = aob + 1048576;         // [2048,2048] bf16 FF hidden
  u16* Wt_voc = h1b + 4194304;         // [32000,512]
  u16* Wt_gkv = Wt_voc + 16384000;     // [1024,512]
  u16* Wt_ff1 = Wt_gkv + 524288;       // 2 x [2048,512]
  u16* Wt_ff2 = Wt_ff1 + 2097152;      // 2 x [512,2048]
  u16* Wt_q   = Wt_ff2 + 2097152;      // 2 x [512,512]
  u16* Wt_k   = Wt_q + 524288;         // 2 x [512,512] (K-half of la_Wkv)
  u16* Wt_o   = Wt_k + 524288;         // 2 x [512,512]
  // split-K partials (<=1MB) alias h1b: h1b is only live between the local-FFN
  // ff1 and ff2 MFMA GEMMs; all k_psum/k_red uses happen outside that span.
  float* P    = (float*)h1b;

  // ---- weight transpose+convert pre-pass (inputs only; graph-safe) ----
  k_wcvt<<<dim3(VOC/32, 16), 256, 0, stream>>>(out_W, VOC, 0, Wt_voc, DM);
  k_wcvt<<<dim3(32, 16),     256, 0, stream>>>(g_Wkv, 1024, 0, Wt_gkv, DM);
  for (int l=0;l<NDEPTH;l++){
    k_wcvt<<<dim3(64, 16), 256, 0, stream>>>(lff_W1 + (size_t)l*DM*FFD, FFD, 0, Wt_ff1 + (size_t)l*1048576, DM);
    k_wcvt<<<dim3(16, 64), 256, 0, stream>>>(lff_W2 + (size_t)l*FFD*DM, DM, 0, Wt_ff2 + (size_t)l*1048576, FFD);
    k_wcvt<<<dim3(16, 16), 256, 0, stream>>>(la_Wq  + (size_t)l*DM*DM, DM, 0, Wt_q + (size_t)l*262144, DM);
    k_wcvt<<<dim3(16, 16), 256, 0, stream>>>(la_Wkv + (size_t)l*DM*1024, 1024, 0, Wt_k + (size_t)l*262144, DM);
    k_wcvt<<<dim3(16, 16), 256, 0, stream>>>(la_Wo  + (size_t)l*DM*DM, DM, 0, Wt_o + (size_t)l*262144, DM);
  }

  k_embed<<<N_TOK*DM/256, 256, 0, stream>>>(tokens, tok_emb, x, xb);
  k_pool <<<NW*DM/256,   256, 0, stream>>>(x, gpos_emb, g);
  k_rotab<<<N_TOK*32/256,256, 0, stream>>>(ct, st);

  for (int l=0;l<NDEPTH;l++){
    // --- global-token transformer (weights shared across layers, fp32 split-K path) ---
    k_ln<false><<<NW,256,0,stream>>>(g, gn, nullptr, g_norm_w, g_norm_b);
    // gkvg = gn @ g_Wkv  [16,1024]
    k_psum<<<dim3(4,8),256,0,stream>>>(gn, DM, g_Wkv, 1024, P, 1024, NW);
    k_red<false,false,false><<<64,256,0,stream>>>(P, 1024, 8, NW, gkvg, 1024, nullptr);
    // gq = gn @ g_Wq  [16,512]
    k_psum<<<dim3(2,8),256,0,stream>>>(gn, DM, g_Wq, 512, P, 512, NW);
    k_red<false,false,false><<<32,256,0,stream>>>(P, 512, 8, NW, gq, 512, nullptr);
    // kvx = x @ g_Wkv (bf16 MFMA)
    k_mgemm<false,false,false,false,true><<<dim3(8,16),256,0,stream>>>(xb, DM, Wt_gkv, qb, 1024, nullptr, 0, nullptr, DM);
    k_gattn<<<NW*NH,64,0,stream>>>(gq, gkvg, qb, gao);
    // g += gao @ g_Wo + bo
    k_psum<<<dim3(2,8),256,0,stream>>>(gao, DM, g_Wo, DM, P, 512, NW);
    k_red<true,true,false><<<32,256,0,stream>>>(P, 512, 8, NW, g, DM, g_bo);
    k_ln<false><<<NW,256,0,stream>>>(g, gn, nullptr, gffnw, gffnb);
    // gh1 = gelu(gn @ gff_W1 + b1)  [16,2048]
    k_psum<<<dim3(8,8),256,0,stream>>>(gn, DM, gff_W1, FFD, P, FFD, NW);
    k_red<true,false,true><<<128,256,0,stream>>>(P, FFD, 8, NW, gh1, FFD, gff_b1);
    // g += gh1 @ gff_W2 + b2  (K=2048)
    k_psum<<<dim3(2,32),256,0,stream>>>(gh1, FFD, gff_W2, DM, P, 512, NW);
    k_red<true,true,false><<<32,256,0,stream>>>(P, 512, 32, NW, g, DM, gff_b2);
    // --- local windowed attention ---
    // gkvl = g[0:15] @ la_Wkv  [15,1024]
    k_psum<<<dim3(4,8),256,0,stream>>>(g, DM, la_Wkv + (size_t)l*DM*1024, 1024, P, 1024, 15);
    k_red<false,false,false><<<64,256,0,stream>>>(P, 1024, 8, 15, gkvl, 1024, nullptr);
    k_ln<true><<<N_TOK,256,0,stream>>>(x, nullptr, xnb, la_nw + l*DM, la_nb + l*DM);
    k_mgemm<false,false,false,false,true><<<dim3(4,16),256,0,stream>>>(xnb, DM, Wt_q + (size_t)l*262144, qb, DM, nullptr, 0, nullptr, DM);
    // only the K half of la_Wkv is live (reference bug: windowed V == windowed K)
    k_mgemm<false,false,false,false,true><<<dim3(4,16),256,0,stream>>>(xnb, DM, Wt_k + (size_t)l*262144, kb, DM, nullptr, 0, nullptr, DM);
    k_rope<<<N_TOK*NH*32/256,256,0,stream>>>(qb, kb, ct, st);
    k_lattn<<<NW*NH,256,0,stream>>>(qb, kb, gkvl, aob);
    k_mgemm<true,true,false,true,true><<<dim3(4,16),256,0,stream>>>(aob, DM, Wt_o + (size_t)l*262144, x, DM, xb, DM, la_bo + l*DM, DM);
    // --- local FFN ---
    k_ln<true><<<N_TOK,256,0,stream>>>(x, nullptr, xnb, lff_nw + l*DM, lff_nb + l*DM);
    k_mgemm<true,false,true,true,false><<<dim3(16,16),256,0,stream>>>(xnb, DM, Wt_ff1 + (size_t)l*1048576, nullptr, 0, h1b, FFD, lff_b1 + l*FFD, DM);
    k_mgemm<true,true,false,true,true><<<dim3(4,16),256,0,stream>>>(h1b, FFD, Wt_ff2 + (size_t)l*1048576, x, DM, xb, DM, lff_b2 + l*DM, FFD);
  }
  // --- output head (bf16 MFMA) ---
  k_ln<true><<<N_TOK,256,0,stream>>>(x, nullptr, xnb, out_nw, out_nb);
  k_mgemm<true,false,false,false,true><<<dim3(VOC/128,16),256,0,stream>>>(xnb, DM, Wt_voc, O, VOC, nullptr, 0, out_b, DM);
}

// Round 12
// 1276.698 us; speedup vs baseline: 2.6886x; 1.2434x over previous
//
#include <hip/hip_runtime.h>
#include <math.h>

#define N_TOK 2048
#define DM    512
#define NW    16
#define WSZ   128
#define NH    8
#define DHD   64
#define FFD   2048
#define VOC   32000
#define NDEPTH 2

typedef unsigned short u16;
typedef unsigned int   u32;
typedef __attribute__((ext_vector_type(8))) short bf16x8;  // 8 bf16 = 4 VGPR
typedef __attribute__((ext_vector_type(4))) float f32x4;

__device__ __forceinline__ float gelu_f(float v){
  return 0.5f*v*(1.0f+erff(v*0.70710678118654752440f));
}
__device__ __forceinline__ u16 f2bf(float f){   // RNE
  u32 u = __float_as_uint(f);
  u += 0x7fffu + ((u >> 16) & 1u);
  return (u16)(u >> 16);
}

// ---------------- prep kernels ----------------
__global__ void k_embed(const int* __restrict__ tok, const float* __restrict__ emb,
                        float* __restrict__ x, u16* __restrict__ xb){
  int idx = blockIdx.x*256 + threadIdx.x;
  int i = idx >> 9, d = idx & 511;
  float v = emb[(size_t)tok[i]*DM + d];
  x[idx] = v;
  xb[idx] = f2bf(v);
}

__global__ void k_pool(const float* __restrict__ x, const float* __restrict__ gpos,
                       float* __restrict__ g){
  int idx = blockIdx.x*256 + threadIdx.x;  // NW*DM
  int w = idx >> 9, d = idx & 511;
  const float* p = x + (size_t)(w*WSZ)*DM + d;
  float s = 0.f;
  #pragma unroll 8
  for (int i=0;i<WSZ;i++) s += p[(size_t)i*DM];
  g[idx] = s*(1.f/WSZ) + gpos[idx];
}

__global__ void k_rotab(float* __restrict__ ct, float* __restrict__ st){
  int idx = blockIdx.x*256 + threadIdx.x; // N_TOK*32
  int i = idx >> 5, j = idx & 31;
  double inv = pow(10000.0, -(double)j/32.0);
  double a = (double)i*inv;
  ct[idx] = (float)cos(a);
  st[idx] = (float)sin(a);
}

__global__ void k_rope(float* __restrict__ q, float* __restrict__ k,
                       const float* __restrict__ ct, const float* __restrict__ st){
  int idx = blockIdx.x*256 + threadIdx.x; // N_TOK*NH*32
  int i = idx >> 8;
  int h = (idx >> 5) & 7;
  int j = idx & 31;
  float c = ct[i*32+j], s = st[i*32+j];
  size_t base = (size_t)i*DM + h*DHD + j;
  float q0=q[base], q1=q[base+32];
  q[base]    = q0*c - q1*s;
  q[base+32] = q1*c + q0*s;
  float k0=k[base], k1=k[base+32];
  k[base]    = k0*c - k1*s;
  k[base+32] = k1*c + k0*s;
}

// LN over rows of length 512; BF=true writes packed bf16, else fp32.
template<bool BF>
__global__ __launch_bounds__(256) void k_ln(const float* __restrict__ in,
                     float* __restrict__ outf, u16* __restrict__ outb,
                     const float* __restrict__ w, const float* __restrict__ b){
  int r = blockIdx.x;
  const float2* p2 = reinterpret_cast<const float2*>(in + (size_t)r*DM);
  float2 v = p2[threadIdx.x];
  float s = v.x+v.y, ss = v.x*v.x + v.y*v.y;
  #pragma unroll
  for (int o=32;o;o>>=1){ s += __shfl_xor(s,o); ss += __shfl_xor(ss,o); }
  __shared__ float sm[4], sm2[4];
  int wv = threadIdx.x >> 6;
  if ((threadIdx.x & 63) == 0){ sm[wv]=s; sm2[wv]=ss; }
  __syncthreads();
  if (threadIdx.x == 0){
    float t=sm[0]+sm[1]+sm[2]+sm[3], t2=sm2[0]+sm2[1]+sm2[2]+sm2[3];
    float mu = t*(1.f/DM);
    float var = t2*(1.f/DM) - mu*mu;
    sm[0]=mu; sm2[0]=rsqrtf(var + 1e-5f);
  }
  __syncthreads();
  float mu = sm[0], rs = sm2[0];
  float2 wv2 = reinterpret_cast<const float2*>(w)[threadIdx.x];
  float2 bv2 = reinterpret_cast<const float2*>(b)[threadIdx.x];
  float ox = (v.x-mu)*rs*wv2.x + bv2.x;
  float oy = (v.y-mu)*rs*wv2.y + bv2.y;
  if (BF){
    reinterpret_cast<u32*>(outb)[(size_t)r*256 + threadIdx.x] =
        (u32)f2bf(ox) | ((u32)f2bf(oy) << 16);
  } else {
    float2 o; o.x = ox; o.y = oy;
    reinterpret_cast<float2*>(outf + (size_t)r*DM)[threadIdx.x] = o;
  }
}

// ---------------- weight transpose+convert: out[n][k] = bf16(in[k][c0+n]) ----------------
// grid (Nt/32, K/32), 256 threads.
__global__ __launch_bounds__(256) void k_wcvt(const float* __restrict__ in, int ldn, int c0,
                        u16* __restrict__ out, int K){
  __shared__ float t[32][33];
  const int tx = threadIdx.x & 31, ty = threadIdx.x >> 5;
  const int n0 = blockIdx.x*32, k0 = blockIdx.y*32;
  #pragma unroll
  for (int r = ty; r < 32; r += 8)
    t[r][tx] = in[(size_t)(k0+r)*ldn + c0 + n0 + tx];
  __syncthreads();
  #pragma unroll
  for (int r = ty; r < 32; r += 8)
    out[(size_t)(n0+r)*K + k0 + tx] = f2bf(t[tx][r]);
}

// ---------------- bf16 MFMA GEMM: C = [gelu](A@B + bias) [+ C] ----------------
// A bf16 [M][lda] row-major; Bt bf16 [N][K] row-major (B pre-transposed).
// 128x128 tile, BK=32, 4 waves each owning 64x64. fp32 accumulate.
template<bool BIAS,bool RES,bool GELU,bool SBF,bool SF32>
__global__ __launch_bounds__(256) void k_mgemm(
    const u16* __restrict__ A, int lda,
    const u16* __restrict__ Bt,
    float* __restrict__ C, int ldc,
    u16* __restrict__ Cb, int ldcb,
    const float* __restrict__ bias, int K)
{
  __shared__ __align__(16) u16 As[128*40];  // row stride 40 bf16 = 80 B (16B-aligned, 2-way banks)
  __shared__ __align__(16) u16 Bs[128*40];
  const int tid = threadIdx.x;
  const int bm0 = blockIdx.y*128, bn0 = blockIdx.x*128;
  const int lane = tid & 63, wid = tid >> 6;
  const int wr = wid >> 1, wc = wid & 1;
  const int r16 = lane & 15, ko = lane >> 4;
  const int srow = tid >> 1, koff = (tid & 1) * 16;
  const u16* Ap = A + (size_t)(bm0 + srow)*lda + koff;
  const u16* Bp = Bt + (size_t)(bn0 + srow)*K + koff;
  const u32 lwa = (u32)srow*40 + (u32)koff;

  f32x4 acc[4][4];
  #pragma unroll
  for (int m=0;m<4;m++)
    #pragma unroll
    for (int n=0;n<4;n++)
      acc[m][n] = (f32x4){0.f,0.f,0.f,0.f};

  for (int kk = 0; kk < K; kk += 32){
    const uint4 a0 = *reinterpret_cast<const uint4*>(Ap + kk);
    const uint4 a1 = *reinterpret_cast<const uint4*>(Ap + kk + 8);
    const uint4 b0 = *reinterpret_cast<const uint4*>(Bp + kk);
    const uint4 b1 = *reinterpret_cast<const uint4*>(Bp + kk + 8);
    *reinterpret_cast<uint4*>(&As[lwa])     = a0;
    *reinterpret_cast<uint4*>(&As[lwa + 8]) = a1;
    *reinterpret_cast<uint4*>(&Bs[lwa])     = b0;
    *reinterpret_cast<uint4*>(&Bs[lwa + 8]) = b1;
    __syncthreads();
    bf16x8 af[4], bfr[4];
    #pragma unroll
    for (int m=0;m<4;m++)
      af[m] = *reinterpret_cast<const bf16x8*>(&As[(u32)(wr*64 + m*16 + r16)*40 + (u32)ko*8]);
    #pragma unroll
    for (int n=0;n<4;n++)
      bfr[n] = *reinterpret_cast<const bf16x8*>(&Bs[(u32)(wc*64 + n*16 + r16)*40 + (u32)ko*8]);
    #pragma unroll
    for (int m=0;m<4;m++)
      #pragma unroll
      for (int n=0;n<4;n++)
        acc[m][n] = __builtin_amdgcn_mfma_f32_16x16x32_bf16(af[m], bfr[n], acc[m][n], 0, 0, 0);
    __syncthreads();
  }

  const int crow0 = bm0 + wr*64, ccol0 = bn0 + wc*64;
  #pragma unroll
  for (int m=0;m<4;m++){
    #pragma unroll
    for (int j=0;j<4;j++){
      const int row = crow0 + m*16 + ko*4 + j;
      #pragma unroll
      for (int n=0;n<4;n++){
        const int col = ccol0 + n*16 + r16;
        float v = acc[m][n][j];
        if (BIAS) v += bias[col];
        if (GELU) v = gelu_f(v);
        if (RES)  v += C[(size_t)row*ldc + col];
        if (SF32) C[(size_t)row*ldc + col] = v;
        if (SBF)  Cb[(size_t)row*ldcb + col] = f2bf(v);
      }
    }
  }
}

// ---------------- small-M GEMM, split-K stage 1 ----------------
// P[s][16][N] partial = A[0:M][s*64:(s+1)*64] @ B[s*64:(s+1)*64][n-chunk]
// grid (N/256, K/64), 256 threads. A fp32 [M][lda] (M<=16), B fp32 [K][ldb].
__global__ __launch_bounds__(256) void k_psum(
    const float* __restrict__ A, int lda,
    const float* __restrict__ B, int ldb,
    float* __restrict__ P, int N, int M)
{
  __shared__ __align__(16) float As[16][68];   // 272B row stride: 16B-aligned
  const int tid = threadIdx.x;
  const int cg = tid & 63, rg = tid >> 6;
  const int n0 = blockIdx.x*256 + cg*4;
  const int k0 = blockIdx.y*64;
  for (int e = tid; e < 16*64; e += 256){
    int r = e >> 6, c = e & 63;
    As[r][c] = (r < M) ? A[(size_t)r*lda + k0 + c] : 0.f;
  }
  __syncthreads();
  float4 acc0 = {0.f,0.f,0.f,0.f}, acc1 = acc0, acc2 = acc0, acc3 = acc0;
  const float* Bp = B + (size_t)k0*ldb + n0;
  #pragma unroll 4
  for (int k4 = 0; k4 < 64; k4 += 4){
    float a0[4], a1[4], a2[4], a3[4];
    *reinterpret_cast<float4*>(a0) = *reinterpret_cast<const float4*>(&As[rg*4+0][k4]);
    *reinterpret_cast<float4*>(a1) = *reinterpret_cast<const float4*>(&As[rg*4+1][k4]);
    *reinterpret_cast<float4*>(a2) = *reinterpret_cast<const float4*>(&As[rg*4+2][k4]);
    *reinterpret_cast<float4*>(a3) = *reinterpret_cast<const float4*>(&As[rg*4+3][k4]);
    #pragma unroll
    for (int j = 0; j < 4; j++){
      const float4 bv = *reinterpret_cast<const float4*>(Bp + (size_t)(k4+j)*ldb);
      acc0.x = fmaf(a0[j], bv.x, acc0.x); acc0.y = fmaf(a0[j], bv.y, acc0.y);
      acc0.z = fmaf(a0[j], bv.z, acc0.z); acc0.w = fmaf(a0[j], bv.w, acc0.w);
      acc1.x = fmaf(a1[j], bv.x, acc1.x); acc1.y = fmaf(a1[j], bv.y, acc1.y);
      acc1.z = fmaf(a1[j], bv.z, acc1.z); acc1.w = fmaf(a1[j], bv.w, acc1.w);
      acc2.x = fmaf(a2[j], bv.x, acc2.x); acc2.y = fmaf(a2[j], bv.y, acc2.y);
      acc2.z = fmaf(a2[j], bv.z, acc2.z); acc2.w = fmaf(a2[j], bv.w, acc2.w);
      acc3.x = fmaf(a3[j], bv.x, acc3.x); acc3.y = fmaf(a3[j], bv.y, acc3.y);
      acc3.z = fmaf(a3[j], bv.z, acc3.z); acc3.w = fmaf(a3[j], bv.w, acc3.w);
    }
  }
  float* Pp = P + ((size_t)blockIdx.y*16 + rg*4)*N + n0;
  *reinterpret_cast<float4*>(Pp)       = acc0;
  *reinterpret_cast<float4*>(Pp + N)   = acc1;
  *reinterpret_cast<float4*>(Pp + 2*N) = acc2;
  *reinterpret_cast<float4*>(Pp + 3*N) = acc3;
}

// ---------------- small-M GEMM, split-K stage 2 (reduce + epilogue) ----------------
template<bool BIAS,bool RES,bool GELU>
__global__ __launch_bounds__(256) void k_red(
    const float* __restrict__ P, int N, int S, int M,
    float* __restrict__ C, int ldc, const float* __restrict__ bias)
{
  int idx = blockIdx.x*256 + threadIdx.x;
  int r = idx / N, n = idx - r*N;
  if (r >= M) return;
  float v = 0.f;
  for (int s = 0; s < S; s++) v += P[((size_t)s*16 + r)*N + n];
  if (BIAS) v += bias[n];
  if (GELU) v = gelu_f(v);
  if (RES)  v += C[(size_t)r*ldc + n];
  C[(size_t)r*ldc + n] = v;
}

// ---------------- global-token attention: 1 query vs 129 keys ----------------
__global__ __launch_bounds__(64) void k_gattn(
    const float* __restrict__ gq, const float* __restrict__ kvg,
    const float* __restrict__ kvx, float* __restrict__ out)
{
  const int w = blockIdx.x >> 3, h = blockIdx.x & 7;
  const int lane = threadIdx.x;
  __shared__ float qs[64];
  __shared__ float p[129];
  qs[lane] = gq[(size_t)w*DM + h*DHD + lane];
  __syncthreads();
  for (int c=0;c<3;c++){
    int j = c*64 + lane;
    if (j < 129){
      const float* kp = (j==0) ? &kvg[(size_t)w*1024 + h*DHD]
                               : &kvx[(size_t)(w*WSZ + j-1)*1024 + h*DHD];
      float s = 0.f;
      for (int d=0;d<64;d++) s = fmaf(qs[d], kp[d], s);
      p[j] = s*0.125f;
    }
  }
  __syncthreads();
  float mx = -3.4e38f;
  for (int j=lane;j<129;j+=64) mx = fmaxf(mx, p[j]);
  #pragma unroll
  for (int o=32;o;o>>=1) mx = fmaxf(mx, __shfl_xor(mx,o));
  float sum = 0.f;
  for (int j=lane;j<129;j+=64){ float e = expf(p[j]-mx); p[j]=e; sum+=e; }
  #pragma unroll
  for (int o=32;o;o>>=1) sum += __shfl_xor(sum,o);
  const float rs = 1.f/sum;
  __syncthreads();
  float o_ = 0.f;
  for (int j=0;j<129;j++){
    const float* vp = (j==0) ? &kvg[(size_t)w*1024 + 512 + h*DHD]
                             : &kvx[(size_t)(w*WSZ + j-1)*1024 + 512 + h*DHD];
    o_ = fmaf(p[j], vp[lane], o_);
  }
  out[(size_t)w*DM + h*DHD + lane] = o_*rs;
}

// ---------------- local windowed attention, MFMA (out -> bf16) ----------------
// grid = NW*NH*2 blocks (w, h, query-half of 64), 256 threads = 4 waves x 16 queries.
// Keys j: 0..14 global (vis j<w), 15..270 local m=j-15 (vis m<=qi+128), 271 pad (masked).
// Local V == local K (closure bug); global V = Gv. S/P fragments per m89 C-layout.
__global__ __launch_bounds__(256) void k_lattn_m(
    const float* __restrict__ q, const float* __restrict__ k,
    const float* __restrict__ gkv, u16* __restrict__ ob)
{
  __shared__ __align__(16) u16 smem[43136];
  __shared__ float rsum[64];
  u16* Ks = smem;           // [272][72]  (keys, bf16; stride 144B -> 2-way banks)
  u16* Qs = smem + 19584;   // [64][72]
  u16* Vt = smem + 24192;   // [64][296]  (V^T: rows=d, cols=key; stride 592B -> 2-way)
  u16* Ps = smem;           // [64][296]  overlays Ks (written after all K reads)
  const int bid = blockIdx.x;
  const int half = bid & 1, h = (bid >> 1) & 7, w = bid >> 4;
  const int tid = threadIdx.x;
  const int lane = tid & 63, wv = tid >> 6;
  const int c16 = lane & 15, ko = lane >> 4;
  const int q0 = w*WSZ + half*64;
  // ---- stage Q [64][64] bf16 ----
  #pragma unroll
  for (int t = 0; t < 16; t++){
    int e = tid + t*256, r = e >> 6, c = e & 63;
    Qs[(u32)r*72 + c] = f2bf(q[(size_t)(q0 + r)*DM + h*DHD + c]);
  }
  // ---- stage K [272][64] bf16 (15 global + 256 local + 1 zero pad) ----
  #pragma unroll
  for (int t = 0; t < 68; t++){
    int e = tid + t*256, r = e >> 6, c = e & 63;
    float v;
    if (r < 15) v = gkv[(size_t)r*1024 + h*DHD + c];
    else if (r < 271){
      int m = r - 15;
      if (m < 128) v = (w == 0) ? 0.f : k[(size_t)((w-1)*WSZ + m)*DM + h*DHD + c];
      else         v = k[(size_t)(w*WSZ + (m-128))*DM + h*DHD + c];
    } else v = 0.f;
    Ks[(u32)r*72 + c] = f2bf(v);
  }
  __syncthreads();
  // ---- build Vt[d][j]: global j -> Gv, local j -> K (closure bug), pad -> 0 ----
  #pragma unroll
  for (int t = 0; t < 72; t++){
    int e = tid + t*256, j = e >> 6, c = e & 63;
    u16 v;
    if (j < 15)       v = f2bf(gkv[(size_t)j*1024 + 512 + h*DHD + c]);
    else if (j < 272) v = Ks[(u32)j*72 + c];
    else              v = 0;
    Vt[(u32)c*296 + j] = v;
  }
  // ---- QK^T: 1 m-tile (16 queries) x 17 n-tiles, K=64 (2 steps) ----
  f32x4 acc[17];
  {
    const bf16x8 aq0 = *reinterpret_cast<const bf16x8*>(&Qs[(u32)(wv*16 + c16)*72 + ko*8]);
    const bf16x8 aq1 = *reinterpret_cast<const bf16x8*>(&Qs[(u32)(wv*16 + c16)*72 + ko*8 + 32]);
    #pragma unroll
    for (int n = 0; n < 17; n++){
      const bf16x8 b0 = *reinterpret_cast<const bf16x8*>(&Ks[(u32)(n*16 + c16)*72 + ko*8]);
      const bf16x8 b1 = *reinterpret_cast<const bf16x8*>(&Ks[(u32)(n*16 + c16)*72 + ko*8 + 32]);
      f32x4 a_ = (f32x4){0.f,0.f,0.f,0.f};
      a_ = __builtin_amdgcn_mfma_f32_16x16x32_bf16(aq0, b0, a_, 0, 0, 0);
      a_ = __builtin_amdgcn_mfma_f32_16x16x32_bf16(aq1, b1, a_, 0, 0, 0);
      acc[n] = a_;
    }
  }
  __syncthreads();   // Vt complete everywhere; all K/Q reads done -> Ps may overwrite
  // ---- mask + scale + in-register softmax (row=(ko*4+jr), col=c16) ----
  float mx[4] = {-3.4e38f,-3.4e38f,-3.4e38f,-3.4e38f};
  #pragma unroll
  for (int n = 0; n < 17; n++){
    const int jkey = n*16 + c16;
    #pragma unroll
    for (int jr = 0; jr < 4; jr++){
      const int qi = half*64 + wv*16 + ko*4 + jr;   // within-window query index
      bool vis;
      if (jkey < 15)        vis = (jkey < w);
      else if (jkey < 271)  vis = ((jkey - 15) <= qi + 128);
      else                  vis = false;
      float s = vis ? acc[n][jr]*0.125f : -3.4e38f;
      acc[n][jr] = s;
      mx[jr] = fmaxf(mx[jr], s);
    }
  }
  #pragma unroll
  for (int o = 1; o < 16; o <<= 1)
    #pragma unroll
    for (int jr = 0; jr < 4; jr++) mx[jr] = fmaxf(mx[jr], __shfl_xor(mx[jr], o));
  float sum[4] = {0.f,0.f,0.f,0.f};
  #pragma unroll
  for (int n = 0; n < 17; n++)
    #pragma unroll
    for (int jr = 0; jr < 4; jr++){
      float p = expf(acc[n][jr] - mx[jr]);   // masked -> exp(-huge)=0
      sum[jr] += p;
      Ps[(u32)(wv*16 + ko*4 + jr)*296 + n*16 + c16] = f2bf(p);
    }
  #pragma unroll
  for (int o = 1; o < 16; o <<= 1)
    #pragma unroll
    for (int jr = 0; jr < 4; jr++) sum[jr] += __shfl_xor(sum[jr], o);
  if (c16 == 0){
    #pragma unroll
    for (int jr = 0; jr < 4; jr++) rsum[wv*16 + ko*4 + jr] = sum[jr];
  }
  // zero own m-tile's P pad cols 272..287 (Vt pad is 0 too, but keep P finite-clean)
  #pragma unroll
  for (int z = 0; z < 4; z++){
    int e = lane + z*64;                 // 256 els: rows wv*16+(e>>4), cols 272+(e&15)
    Ps[(u32)(wv*16 + (e >> 4))*296 + 272 + (e & 15)] = 0;
  }
  // ---- PV: O[16q][64d] = P[16][288] @ V[288][64]; K-loop 9, n-tiles 4 ----
  f32x4 o_[4];
  #pragma unroll
  for (int n = 0; n < 4; n++) o_[n] = (f32x4){0.f,0.f,0.f,0.f};
  #pragma unroll
  for (int ks = 0; ks < 9; ks++){
    const bf16x8 ap = *reinterpret_cast<const bf16x8*>(&Ps[(u32)(wv*16 + c16)*296 + ko*8 + ks*32]);
    #pragma unroll
    for (int n = 0; n < 4; n++){
      const bf16x8 bv = *reinterpret_cast<const bf16x8*>(&Vt[(u32)(n*16 + c16)*296 + ko*8 + ks*32]);
      o_[n] = __builtin_amdgcn_mfma_f32_16x16x32_bf16(ap, bv, o_[n], 0, 0, 0);
    }
  }
  // ---- epilogue: divide by rowsum, store bf16 ----
  #pragma unroll
  for (int jr = 0; jr < 4; jr++){
    const int r = wv*16 + ko*4 + jr;
    const float rs = 1.f / rsum[r];
    #pragma unroll
    for (int n = 0; n < 4; n++)
      ob[(size_t)(q0 + r)*DM + h*DHD + n*16 + c16] = f2bf(o_[n][jr] * rs);
  }
}

// ---------------- launch ----------------
extern "C" void kernel_launch(void* const* d_in, const int* in_sizes, int n_in,
                              void* d_out, int out_size, void* d_ws, size_t ws_size,
                              hipStream_t stream)
{
  (void)in_sizes; (void)n_in; (void)out_size; (void)ws_size;
  const int*   tokens   = (const int*)  d_in[0];
  const float* tok_emb  = (const float*)d_in[1];
  const float* gpos_emb = (const float*)d_in[2];
  const float* g_norm_w = (const float*)d_in[3];
  const float* g_norm_b = (const float*)d_in[4];
  const float* g_Wq     = (const float*)d_in[5];
  const float* g_Wkv    = (const float*)d_in[6];
  const float* g_Wo     = (const float*)d_in[7];
  const float* g_bo     = (const float*)d_in[8];
  const float* gffnw    = (const float*)d_in[9];
  const float* gffnb    = (const float*)d_in[10];
  const float* gff_W1   = (const float*)d_in[11];
  const float* gff_b1   = (const float*)d_in[12];
  const float* gff_W2   = (const float*)d_in[13];
  const float* gff_b2   = (const float*)d_in[14];
  const float* la_nw    = (const float*)d_in[15];
  const float* la_nb    = (const float*)d_in[16];
  const float* la_Wq    = (const float*)d_in[17];
  const float* la_Wkv   = (const float*)d_in[18];
  const float* la_Wo    = (const float*)d_in[19];
  const float* la_bo    = (const float*)d_in[20];
  const float* lff_nw   = (const float*)d_in[21];
  const float* lff_nb   = (const float*)d_in[22];
  const float* lff_W1   = (const float*)d_in[23];
  const float* lff_b1   = (const float*)d_in[24];
  const float* lff_W2   = (const float*)d_in[25];
  const float* lff_b2   = (const float*)d_in[26];
  const float* out_nw   = (const float*)d_in[27];
  const float* out_nb   = (const float*)d_in[28];
  const float* out_W    = (const float*)d_in[29];
  const float* out_b    = (const float*)d_in[30];
  float* O = (float*)d_out;

  float* ws = (float*)d_ws;
  float* x    = ws;                    // [2048,512] fp32 residual
  float* qb   = x + 1048576;           // [2048,512] q fp32 (qb..kb also = kvx [2048,1024])
  float* kb   = qb + 1048576;          // [2048,512] k fp32
  float* g    = kb + 1048576;          // [16,512]
  float* gn   = g + 8192;
  float* gq   = gn + 8192;
  float* gao  = gq + 8192;
  float* gkvg = gao + 8192;            // [16,1024]
  float* gh1  = gkvg + 16384;          // [16,2048]
  float* gkvl = gh1 + 32768;           // [15,1024]
  float* ct   = gkvl + 15360;          // [2048,32]
  float* st   = ct + 65536;
  u16* xb     = (u16*)(st + 65536);    // [2048,512] bf16 residual copy
  u16* xnb    = xb + 1048576;          // [2048,512] bf16 LN out
  u16* aob    = xnb + 1048576;         // [2048,512] bf16 attn out
  u16* h1b    = aob + 1048576;         // [2048,2048] bf16 FF hidden
  u16* Wt_voc = h1b + 4194304;         // [32000,512]
  u16* Wt_gkv = Wt_voc + 16384000;     // [1024,512]
  u16* Wt_ff1 = Wt_gkv + 524288;       // 2 x [2048,512]
  u16* Wt_ff2 = Wt_ff1 + 2097152;      // 2 x [512,2048]
  u16* Wt_q   = Wt_ff2 + 2097152;      // 2 x [512,512]
  u16* Wt_k   = Wt_q + 524288;         // 2 x [512,512] (K-half of la_Wkv)
  u16* Wt_o   = Wt_k + 524288;         // 2 x [512,512]
  // split-K partials (<=1MB) alias h1b (only live ff1->ff2 inside local FFN)
  float* P    = (float*)h1b;

  // ---- weight transpose+convert pre-pass (inputs only; graph-safe) ----
  k_wcvt<<<dim3(VOC/32, 16), 256, 0, stream>>>(out_W, VOC, 0, Wt_voc, DM);
  k_wcvt<<<dim3(32, 16),     256, 0, stream>>>(g_Wkv, 1024, 0, Wt_gkv, DM);
  for (int l=0;l<NDEPTH;l++){
    k_wcvt<<<dim3(64, 16), 256, 0, stream>>>(lff_W1 + (size_t)l*DM*FFD, FFD, 0, Wt_ff1 + (size_t)l*1048576, DM);
    k_wcvt<<<dim3(16, 64), 256, 0, stream>>>(lff_W2 + (size_t)l*FFD*DM, DM, 0, Wt_ff2 + (size_t)l*1048576, FFD);
    k_wcvt<<<dim3(16, 16), 256, 0, stream>>>(la_Wq  + (size_t)l*DM*DM, DM, 0, Wt_q + (size_t)l*262144, DM);
    k_wcvt<<<dim3(16, 16), 256, 0, stream>>>(la_Wkv + (size_t)l*DM*1024, 1024, 0, Wt_k + (size_t)l*262144, DM);
    k_wcvt<<<dim3(16, 16), 256, 0, stream>>>(la_Wo  + (size_t)l*DM*DM, DM, 0, Wt_o + (size_t)l*262144, DM);
  }

  k_embed<<<N_TOK*DM/256, 256, 0, stream>>>(tokens, tok_emb, x, xb);
  k_pool <<<NW*DM/256,   256, 0, stream>>>(x, gpos_emb, g);
  k_rotab<<<N_TOK*32/256,256, 0, stream>>>(ct, st);

  for (int l=0;l<NDEPTH;l++){
    // --- global-token transformer (weights shared across layers, fp32 split-K path) ---
    k_ln<false><<<NW,256,0,stream>>>(g, gn, nullptr, g_norm_w, g_norm_b);
    k_psum<<<dim3(4,8),256,0,stream>>>(gn, DM, g_Wkv, 1024, P, 1024, NW);
    k_red<false,false,false><<<64,256,0,stream>>>(P, 1024, 8, NW, gkvg, 1024, nullptr);
    k_psum<<<dim3(2,8),256,0,stream>>>(gn, DM, g_Wq, 512, P, 512, NW);
    k_red<false,false,false><<<32,256,0,stream>>>(P, 512, 8, NW, gq, 512, nullptr);
    // kvx = x @ g_Wkv (bf16 MFMA)
    k_mgemm<false,false,false,false,true><<<dim3(8,16),256,0,stream>>>(xb, DM, Wt_gkv, qb, 1024, nullptr, 0, nullptr, DM);
    k_gattn<<<NW*NH,64,0,stream>>>(gq, gkvg, qb, gao);
    k_psum<<<dim3(2,8),256,0,stream>>>(gao, DM, g_Wo, DM, P, 512, NW);
    k_red<true,true,false><<<32,256,0,stream>>>(P, 512, 8, NW, g, DM, g_bo);
    k_ln<false><<<NW,256,0,stream>>>(g, gn, nullptr, gffnw, gffnb);
    k_psum<<<dim3(8,8),256,0,stream>>>(gn, DM, gff_W1, FFD, P, FFD, NW);
    k_red<true,false,true><<<128,256,0,stream>>>(P, FFD, 8, NW, gh1, FFD, gff_b1);
    k_psum<<<dim3(2,32),256,0,stream>>>(gh1, FFD, gff_W2, DM, P, 512, NW);
    k_red<true,true,false><<<32,256,0,stream>>>(P, 512, 32, NW, g, DM, gff_b2);
    // --- local windowed attention ---
    k_psum<<<dim3(4,8),256,0,stream>>>(g, DM, la_Wkv + (size_t)l*DM*1024, 1024, P, 1024, 15);
    k_red<false,false,false><<<64,256,0,stream>>>(P, 1024, 8, 15, gkvl, 1024, nullptr);
    k_ln<true><<<N_TOK,256,0,stream>>>(x, nullptr, xnb, la_nw + l*DM, la_nb + l*DM);
    k_mgemm<false,false,false,false,true><<<dim3(4,16),256,0,stream>>>(xnb, DM, Wt_q + (size_t)l*262144, qb, DM, nullptr, 0, nullptr, DM);
    // only the K half of la_Wkv is live (reference bug: windowed V == windowed K)
    k_mgemm<false,false,false,false,true><<<dim3(4,16),256,0,stream>>>(xnb, DM, Wt_k + (size_t)l*262144, kb, DM, nullptr, 0, nullptr, DM);
    k_rope<<<N_TOK*NH*32/256,256,0,stream>>>(qb, kb, ct, st);
    k_lattn_m<<<NW*NH*2,256,0,stream>>>(qb, kb, gkvl, aob);
    k_mgemm<true,true,false,true,true><<<dim3(4,16),256,0,stream>>>(aob, DM, Wt_o + (size_t)l*262144, x, DM, xb, DM, la_bo + l*DM, DM);
    // --- local FFN ---
    k_ln<true><<<N_TOK,256,0,stream>>>(x, nullptr, xnb, lff_nw + l*DM, lff_nb + l*DM);
    k_mgemm<true,false,true,true,false><<<dim3(16,16),256,0,stream>>>(xnb, DM, Wt_ff1 + (size_t)l*1048576, nullptr, 0, h1b, FFD, lff_b1 + l*FFD, DM);
    k_mgemm<true,true,false,true,true><<<dim3(4,16),256,0,stream>>>(h1b, FFD, Wt_ff2 + (size_t)l*1048576, x, DM, xb, DM, lff_b2 + l*DM, FFD);
  }
  // --- output head (bf16 MFMA) ---
  k_ln<true><<<N_TOK,256,0,stream>>>(x, nullptr, xnb, out_nw, out_nb);
  k_mgemm<true,false,false,false,true><<<dim3(VOC/128,16),256,0,stream>>>(xnb, DM, Wt_voc, O, VOC, nullptr, 0, out_b, DM);
}

// Round 13
// 1152.840 us; speedup vs baseline: 2.9774x; 1.1074x over previous
//
#include <hip/hip_runtime.h>
#include <math.h>

#define N_TOK 2048
#define DM    512
#define NW    16
#define WSZ   128
#define NH    8
#define DHD   64
#define FFD   2048
#define VOC   32000
#define NDEPTH 2

typedef unsigned short u16;
typedef unsigned int   u32;
typedef __attribute__((ext_vector_type(8))) short bf16x8;  // 8 bf16 = 4 VGPR
typedef __attribute__((ext_vector_type(4))) float f32x4;

__device__ __forceinline__ float gelu_f(float v){
  return 0.5f*v*(1.0f+erff(v*0.70710678118654752440f));
}
__device__ __forceinline__ u16 f2bf(float f){   // RNE
  u32 u = __float_as_uint(f);
  u += 0x7fffu + ((u >> 16) & 1u);
  return (u16)(u >> 16);
}
// async global->LDS, 16B per lane; lds dest must be wave-uniform base (+lane*16 by HW)
__device__ __forceinline__ void gld16(const u16* g, u16* l){
  __builtin_amdgcn_global_load_lds(
      (const __attribute__((address_space(1))) u32*)g,
      (__attribute__((address_space(3))) u32*)l, 16, 0, 0);
}

// ---------------- prep kernels ----------------
__global__ void k_embed(const int* __restrict__ tok, const float* __restrict__ emb,
                        float* __restrict__ x, u16* __restrict__ xb){
  int idx = blockIdx.x*256 + threadIdx.x;
  int i = idx >> 9, d = idx & 511;
  float v = emb[(size_t)tok[i]*DM + d];
  x[idx] = v;
  xb[idx] = f2bf(v);
}

__global__ void k_pool(const float* __restrict__ x, const float* __restrict__ gpos,
                       float* __restrict__ g){
  int idx = blockIdx.x*256 + threadIdx.x;  // NW*DM
  int w = idx >> 9, d = idx & 511;
  const float* p = x + (size_t)(w*WSZ)*DM + d;
  float s = 0.f;
  #pragma unroll 8
  for (int i=0;i<WSZ;i++) s += p[(size_t)i*DM];
  g[idx] = s*(1.f/WSZ) + gpos[idx];
}

__global__ void k_rotab(float* __restrict__ ct, float* __restrict__ st){
  int idx = blockIdx.x*256 + threadIdx.x; // N_TOK*32
  int i = idx >> 5, j = idx & 31;
  double inv = pow(10000.0, -(double)j/32.0);
  double a = (double)i*inv;
  ct[idx] = (float)cos(a);
  st[idx] = (float)sin(a);
}

__global__ void k_rope(float* __restrict__ q, float* __restrict__ k,
                       const float* __restrict__ ct, const float* __restrict__ st){
  int idx = blockIdx.x*256 + threadIdx.x; // N_TOK*NH*32
  int i = idx >> 8;
  int h = (idx >> 5) & 7;
  int j = idx & 31;
  float c = ct[i*32+j], s = st[i*32+j];
  size_t base = (size_t)i*DM + h*DHD + j;
  float q0=q[base], q1=q[base+32];
  q[base]    = q0*c - q1*s;
  q[base+32] = q1*c + q0*s;
  float k0=k[base], k1=k[base+32];
  k[base]    = k0*c - k1*s;
  k[base+32] = k1*c + k0*s;
}

// LN over rows of length 512; BF=true writes packed bf16, else fp32.
template<bool BF>
__global__ __launch_bounds__(256) void k_ln(const float* __restrict__ in,
                     float* __restrict__ outf, u16* __restrict__ outb,
                     const float* __restrict__ w, const float* __restrict__ b){
  int r = blockIdx.x;
  const float2* p2 = reinterpret_cast<const float2*>(in + (size_t)r*DM);
  float2 v = p2[threadIdx.x];
  float s = v.x+v.y, ss = v.x*v.x + v.y*v.y;
  #pragma unroll
  for (int o=32;o;o>>=1){ s += __shfl_xor(s,o); ss += __shfl_xor(ss,o); }
  __shared__ float sm[4], sm2[4];
  int wv = threadIdx.x >> 6;
  if ((threadIdx.x & 63) == 0){ sm[wv]=s; sm2[wv]=ss; }
  __syncthreads();
  if (threadIdx.x == 0){
    float t=sm[0]+sm[1]+sm[2]+sm[3], t2=sm2[0]+sm2[1]+sm2[2]+sm2[3];
    float mu = t*(1.f/DM);
    float var = t2*(1.f/DM) - mu*mu;
    sm[0]=mu; sm2[0]=rsqrtf(var + 1e-5f);
  }
  __syncthreads();
  float mu = sm[0], rs = sm2[0];
  float2 wv2 = reinterpret_cast<const float2*>(w)[threadIdx.x];
  float2 bv2 = reinterpret_cast<const float2*>(b)[threadIdx.x];
  float ox = (v.x-mu)*rs*wv2.x + bv2.x;
  float oy = (v.y-mu)*rs*wv2.y + bv2.y;
  if (BF){
    reinterpret_cast<u32*>(outb)[(size_t)r*256 + threadIdx.x] =
        (u32)f2bf(ox) | ((u32)f2bf(oy) << 16);
  } else {
    float2 o; o.x = ox; o.y = oy;
    reinterpret_cast<float2*>(outf + (size_t)r*DM)[threadIdx.x] = o;
  }
}

// ---------------- weight transpose+convert: out[n][k] = bf16(in[k][c0+n]) ----------------
// grid (Nt/32, K/32), 256 threads.
__global__ __launch_bounds__(256) void k_wcvt(const float* __restrict__ in, int ldn, int c0,
                        u16* __restrict__ out, int K){
  __shared__ float t[32][33];
  const int tx = threadIdx.x & 31, ty = threadIdx.x >> 5;
  const int n0 = blockIdx.x*32, k0 = blockIdx.y*32;
  #pragma unroll
  for (int r = ty; r < 32; r += 8)
    t[r][tx] = in[(size_t)(k0+r)*ldn + c0 + n0 + tx];
  __syncthreads();
  #pragma unroll
  for (int r = ty; r < 32; r += 8)
    out[(size_t)(n0+r)*K + k0 + tx] = f2bf(t[tx][r]);
}

// ---------------- bf16 MFMA GEMM: C = [gelu](A@B + bias) [+ C] ----------------
// A bf16 [M][lda] row-major; Bt bf16 [N][K] row-major (B pre-transposed).
// BMxBN tile (64/128 each), BK=64, 4 waves in 2x2, each owning (BM/2)x(BN/2).
// Staging: global_load_lds 16B/lane into unpadded 128B rows; chunk-XOR swizzle
// chunk^= (row&7) applied on global SOURCE (write side) and on fragment reads
// (both-sides rule) -> bank-uniform b128 reads, bijective, bit-exact math.
template<int BM,int BN,bool BIAS,bool RES,bool GELU,bool SBF,bool SF32>
__global__ __launch_bounds__(256) void k_mgemm(
    const u16* __restrict__ A, int lda,
    const u16* __restrict__ Bt,
    float* __restrict__ C, int ldc,
    u16* __restrict__ Cb, int ldcb,
    const float* __restrict__ bias, int K)
{
  constexpr int WM = BM/2, WN = BN/2;
  constexpr int MF = WM/16, NF = WN/16;
  constexpr int AL = BM/32, BL = BN/32;   // wave-loads per K-step (8 rows each)
  __shared__ __align__(128) u16 As[BM*64];
  __shared__ __align__(128) u16 Bs[BN*64];
  const int tid = threadIdx.x;
  const int bm0 = blockIdx.y*BM, bn0 = blockIdx.x*BN;
  const int lane = tid & 63, wid = tid >> 6;
  const int wr = wid >> 1, wc = wid & 1;
  const int r16 = lane & 15, ko = lane >> 4;
  const int lr8 = lane >> 3, lc8 = lane & 7;

  f32x4 acc[MF][NF];
  #pragma unroll
  for (int m=0;m<MF;m++)
    #pragma unroll
    for (int n=0;n<NF;n++)
      acc[m][n] = (f32x4){0.f,0.f,0.f,0.f};

  for (int kk = 0; kk < K; kk += 64){
    #pragma unroll
    for (int t=0;t<AL;t++){
      const int R = wid*(BM/4) + t*8;
      const int rl = R + lr8;
      const int ch = lc8 ^ (rl & 7);
      gld16(A + (size_t)(bm0 + rl)*lda + kk + ch*8, &As[(u32)R*64]);
    }
    #pragma unroll
    for (int t=0;t<BL;t++){
      const int R = wid*(BN/4) + t*8;
      const int rl = R + lr8;
      const int ch = lc8 ^ (rl & 7);
      gld16(Bt + (size_t)(bn0 + rl)*K + kk + ch*8, &Bs[(u32)R*64]);
    }
    __syncthreads();   // compiler drains vmcnt before barrier -> LDS image complete
    #pragma unroll
    for (int h=0;h<2;h++){
      bf16x8 af[MF], bfr[NF];
      #pragma unroll
      for (int m=0;m<MF;m++){
        const int ra = wr*WM + m*16 + r16;
        af[m] = *reinterpret_cast<const bf16x8*>(&As[(u32)ra*64 + (u32)(((ko + 4*h) ^ (ra & 7))*8)]);
      }
      #pragma unroll
      for (int n=0;n<NF;n++){
        const int rb = wc*WN + n*16 + r16;
        bfr[n] = *reinterpret_cast<const bf16x8*>(&Bs[(u32)rb*64 + (u32)(((ko + 4*h) ^ (rb & 7))*8)]);
      }
      #pragma unroll
      for (int m=0;m<MF;m++)
        #pragma unroll
        for (int n=0;n<NF;n++)
          acc[m][n] = __builtin_amdgcn_mfma_f32_16x16x32_bf16(af[m], bfr[n], acc[m][n], 0, 0, 0);
    }
    __syncthreads();
  }

  const int crow0 = bm0 + wr*WM, ccol0 = bn0 + wc*WN;
  #pragma unroll
  for (int m=0;m<MF;m++){
    #pragma unroll
    for (int j=0;j<4;j++){
      const int row = crow0 + m*16 + ko*4 + j;
      #pragma unroll
      for (int n=0;n<NF;n++){
        const int col = ccol0 + n*16 + r16;
        float v = acc[m][n][j];
        if (BIAS) v += bias[col];
        if (GELU) v = gelu_f(v);
        if (RES)  v += C[(size_t)row*ldc + col];
        if (SF32) C[(size_t)row*ldc + col] = v;
        if (SBF)  Cb[(size_t)row*ldcb + col] = f2bf(v);
      }
    }
  }
}

// ---------------- small-M GEMM, split-K stage 1 ----------------
// P[s][16][N] partial = A[0:M][s*64:(s+1)*64] @ B[s*64:(s+1)*64][n-chunk]
// grid (N/256, K/64), 256 threads. A fp32 [M][lda] (M<=16), B fp32 [K][ldb].
__global__ __launch_bounds__(256) void k_psum(
    const float* __restrict__ A, int lda,
    const float* __restrict__ B, int ldb,
    float* __restrict__ P, int N, int M)
{
  __shared__ __align__(16) float As[16][68];   // 272B row stride: 16B-aligned
  const int tid = threadIdx.x;
  const int cg = tid & 63, rg = tid >> 6;
  const int n0 = blockIdx.x*256 + cg*4;
  const int k0 = blockIdx.y*64;
  for (int e = tid; e < 16*64; e += 256){
    int r = e >> 6, c = e & 63;
    As[r][c] = (r < M) ? A[(size_t)r*lda + k0 + c] : 0.f;
  }
  __syncthreads();
  float4 acc0 = {0.f,0.f,0.f,0.f}, acc1 = acc0, acc2 = acc0, acc3 = acc0;
  const float* Bp = B + (size_t)k0*ldb + n0;
  #pragma unroll 4
  for (int k4 = 0; k4 < 64; k4 += 4){
    float a0[4], a1[4], a2[4], a3[4];
    *reinterpret_cast<float4*>(a0) = *reinterpret_cast<const float4*>(&As[rg*4+0][k4]);
    *reinterpret_cast<float4*>(a1) = *reinterpret_cast<const float4*>(&As[rg*4+1][k4]);
    *reinterpret_cast<float4*>(a2) = *reinterpret_cast<const float4*>(&As[rg*4+2][k4]);
    *reinterpret_cast<float4*>(a3) = *reinterpret_cast<const float4*>(&As[rg*4+3][k4]);
    #pragma unroll
    for (int j = 0; j < 4; j++){
      const float4 bv = *reinterpret_cast<const float4*>(Bp + (size_t)(k4+j)*ldb);
      acc0.x = fmaf(a0[j], bv.x, acc0.x); acc0.y = fmaf(a0[j], bv.y, acc0.y);
      acc0.z = fmaf(a0[j], bv.z, acc0.z); acc0.w = fmaf(a0[j], bv.w, acc0.w);
      acc1.x = fmaf(a1[j], bv.x, acc1.x); acc1.y = fmaf(a1[j], bv.y, acc1.y);
      acc1.z = fmaf(a1[j], bv.z, acc1.z); acc1.w = fmaf(a1[j], bv.w, acc1.w);
      acc2.x = fmaf(a2[j], bv.x, acc2.x); acc2.y = fmaf(a2[j], bv.y, acc2.y);
      acc2.z = fmaf(a2[j], bv.z, acc2.z); acc2.w = fmaf(a2[j], bv.w, acc2.w);
      acc3.x = fmaf(a3[j], bv.x, acc3.x); acc3.y = fmaf(a3[j], bv.y, acc3.y);
      acc3.z = fmaf(a3[j], bv.z, acc3.z); acc3.w = fmaf(a3[j], bv.w, acc3.w);
    }
  }
  float* Pp = P + ((size_t)blockIdx.y*16 + rg*4)*N + n0;
  *reinterpret_cast<float4*>(Pp)       = acc0;
  *reinterpret_cast<float4*>(Pp + N)   = acc1;
  *reinterpret_cast<float4*>(Pp + 2*N) = acc2;
  *reinterpret_cast<float4*>(Pp + 3*N) = acc3;
}

// ---------------- small-M GEMM, split-K stage 2 (reduce + epilogue) ----------------
template<bool BIAS,bool RES,bool GELU>
__global__ __launch_bounds__(256) void k_red(
    const float* __restrict__ P, int N, int S, int M,
    float* __restrict__ C, int ldc, const float* __restrict__ bias)
{
  int idx = blockIdx.x*256 + threadIdx.x;
  int r = idx / N, n = idx - r*N;
  if (r >= M) return;
  float v = 0.f;
  for (int s = 0; s < S; s++) v += P[((size_t)s*16 + r)*N + n];
  if (BIAS) v += bias[n];
  if (GELU) v = gelu_f(v);
  if (RES)  v += C[(size_t)r*ldc + n];
  C[(size_t)r*ldc + n] = v;
}

// ---------------- global-token attention: 1 query vs 129 keys (K/V LDS-staged) ----------------
__global__ __launch_bounds__(64) void k_gattn(
    const float* __restrict__ gq, const float* __restrict__ kvg,
    const float* __restrict__ kvx, float* __restrict__ out)
{
  const int w = blockIdx.x >> 3, h = blockIdx.x & 7;
  const int lane = threadIdx.x;
  __shared__ float qs[64];
  __shared__ float p[129];
  __shared__ float KV[129][65];   // +1 pad: score phase reads rows per-lane conflict-free
  qs[lane] = gq[(size_t)w*DM + h*DHD + lane];
  // stage K (coalesced 256B rows; independent loads pipeline)
  for (int e = lane; e < 129*64; e += 64){
    int j = e >> 6, d = e & 63;
    KV[j][d] = (j==0) ? kvg[(size_t)w*1024 + h*DHD + d]
                      : kvx[(size_t)(w*WSZ + j-1)*1024 + h*DHD + d];
  }
  __syncthreads();
  for (int c=0;c<3;c++){
    int j = c*64 + lane;
    if (j < 129){
      float s = 0.f;
      #pragma unroll
      for (int d=0;d<64;d++) s = fmaf(qs[d], KV[j][d], s);
      p[j] = s*0.125f;
    }
  }
  __syncthreads();
  float mx = -3.4e38f;
  for (int j=lane;j<129;j+=64) mx = fmaxf(mx, p[j]);
  #pragma unroll
  for (int o=32;o;o>>=1) mx = fmaxf(mx, __shfl_xor(mx,o));
  float sum = 0.f;
  for (int j=lane;j<129;j+=64){ float e = expf(p[j]-mx); p[j]=e; sum+=e; }
  #pragma unroll
  for (int o=32;o;o>>=1) sum += __shfl_xor(sum,o);
  const float rs = 1.f/sum;
  __syncthreads();
  // stage V over KV (1-wave block: program order makes this race-free)
  for (int e = lane; e < 129*64; e += 64){
    int j = e >> 6, d = e & 63;
    KV[j][d] = (j==0) ? kvg[(size_t)w*1024 + 512 + h*DHD + d]
                      : kvx[(size_t)(w*WSZ + j-1)*1024 + 512 + h*DHD + d];
  }
  __syncthreads();
  float o_ = 0.f;
  #pragma unroll 8
  for (int j=0;j<129;j++) o_ = fmaf(p[j], KV[j][lane], o_);
  out[(size_t)w*DM + h*DHD + lane] = o_*rs;
}

// ---------------- local windowed attention, MFMA (out -> bf16) ----------------
// grid = NW*NH*2 blocks (w, h, query-half of 64), 256 threads = 4 waves x 16 queries.
// Keys j: 0..14 global (vis j<w), 15..270 local m=j-15 (vis m<=qi+128), 271 pad (masked).
// Local V == local K (closure bug); global V = Gv. S/P fragments per m89 C-layout.
__global__ __launch_bounds__(256) void k_lattn_m(
    const float* __restrict__ q, const float* __restrict__ k,
    const float* __restrict__ gkv, u16* __restrict__ ob)
{
  __shared__ __align__(16) u16 smem[43136];
  __shared__ float rsum[64];
  u16* Ks = smem;           // [272][72]  (keys, bf16; stride 144B -> 2-way banks)
  u16* Qs = smem + 19584;   // [64][72]
  u16* Vt = smem + 24192;   // [64][296]  (V^T: rows=d, cols=key; stride 592B -> 2-way)
  u16* Ps = smem;           // [64][296]  overlays Ks (written after all K reads)
  const int bid = blockIdx.x;
  const int half = bid & 1, h = (bid >> 1) & 7, w = bid >> 4;
  const int tid = threadIdx.x;
  const int lane = tid & 63, wv = tid >> 6;
  const int c16 = lane & 15, ko = lane >> 4;
  const int q0 = w*WSZ + half*64;
  // ---- stage Q [64][64] bf16 ----
  #pragma unroll
  for (int t = 0; t < 16; t++){
    int e = tid + t*256, r = e >> 6, c = e & 63;
    Qs[(u32)r*72 + c] = f2bf(q[(size_t)(q0 + r)*DM + h*DHD + c]);
  }
  // ---- stage K [272][64] bf16 (15 global + 256 local + 1 zero pad) ----
  #pragma unroll
  for (int t = 0; t < 68; t++){
    int e = tid + t*256, r = e >> 6, c = e & 63;
    float v;
    if (r < 15) v = gkv[(size_t)r*1024 + h*DHD + c];
    else if (r < 271){
      int m = r - 15;
      if (m < 128) v = (w == 0) ? 0.f : k[(size_t)((w-1)*WSZ + m)*DM + h*DHD + c];
      else         v = k[(size_t)(w*WSZ + (m-128))*DM + h*DHD + c];
    } else v = 0.f;
    Ks[(u32)r*72 + c] = f2bf(v);
  }
  __syncthreads();
  // ---- build Vt[d][j]: global j -> Gv, local j -> K (closure bug), pad -> 0 ----
  #pragma unroll
  for (int t = 0; t < 72; t++){
    int e = tid + t*256, j = e >> 6, c = e & 63;
    u16 v;
    if (j < 15)       v = f2bf(gkv[(size_t)j*1024 + 512 + h*DHD + c]);
    else if (j < 272) v = Ks[(u32)j*72 + c];
    else              v = 0;
    Vt[(u32)c*296 + j] = v;
  }
  // ---- QK^T: 1 m-tile (16 queries) x 17 n-tiles, K=64 (2 steps) ----
  f32x4 acc[17];
  {
    const bf16x8 aq0 = *reinterpret_cast<const bf16x8*>(&Qs[(u32)(wv*16 + c16)*72 + ko*8]);
    const bf16x8 aq1 = *reinterpret_cast<const bf16x8*>(&Qs[(u32)(wv*16 + c16)*72 + ko*8 + 32]);
    #pragma unroll
    for (int n = 0; n < 17; n++){
      const bf16x8 b0 = *reinterpret_cast<const bf16x8*>(&Ks[(u32)(n*16 + c16)*72 + ko*8]);
      const bf16x8 b1 = *reinterpret_cast<const bf16x8*>(&Ks[(u32)(n*16 + c16)*72 + ko*8 + 32]);
      f32x4 a_ = (f32x4){0.f,0.f,0.f,0.f};
      a_ = __builtin_amdgcn_mfma_f32_16x16x32_bf16(aq0, b0, a_, 0, 0, 0);
      a_ = __builtin_amdgcn_mfma_f32_16x16x32_bf16(aq1, b1, a_, 0, 0, 0);
      acc[n] = a_;
    }
  }
  __syncthreads();   // Vt complete everywhere; all K/Q reads done -> Ps may overwrite
  // ---- mask + scale + in-register softmax (row=(ko*4+jr), col=c16) ----
  float mx[4] = {-3.4e38f,-3.4e38f,-3.4e38f,-3.4e38f};
  #pragma unroll
  for (int n = 0; n < 17; n++){
    const int jkey = n*16 + c16;
    #pragma unroll
    for (int jr = 0; jr < 4; jr++){
      const int qi = half*64 + wv*16 + ko*4 + jr;   // within-window query index
      bool vis;
      if (jkey < 15)        vis = (jkey < w);
      else if (jkey < 271)  vis = ((jkey - 15) <= qi + 128);
      else                  vis = false;
      float s = vis ? acc[n][jr]*0.125f : -3.4e38f;
      acc[n][jr] = s;
      mx[jr] = fmaxf(mx[jr], s);
    }
  }
  #pragma unroll
  for (int o = 1; o < 16; o <<= 1)
    #pragma unroll
    for (int jr = 0; jr < 4; jr++) mx[jr] = fmaxf(mx[jr], __shfl_xor(mx[jr], o));
  float sum[4] = {0.f,0.f,0.f,0.f};
  #pragma unroll
  for (int n = 0; n < 17; n++)
    #pragma unroll
    for (int jr = 0; jr < 4; jr++){
      float p = expf(acc[n][jr] - mx[jr]);   // masked -> exp(-huge)=0
      sum[jr] += p;
      Ps[(u32)(wv*16 + ko*4 + jr)*296 + n*16 + c16] = f2bf(p);
    }
  #pragma unroll
  for (int o = 1; o < 16; o <<= 1)
    #pragma unroll
    for (int jr = 0; jr < 4; jr++) sum[jr] += __shfl_xor(sum[jr], o);
  if (c16 == 0){
    #pragma unroll
    for (int jr = 0; jr < 4; jr++) rsum[wv*16 + ko*4 + jr] = sum[jr];
  }
  // zero own m-tile's P pad cols 272..287 (Vt pad is 0 too, but keep P finite-clean)
  #pragma unroll
  for (int z = 0; z < 4; z++){
    int e = lane + z*64;                 // 256 els: rows wv*16+(e>>4), cols 272+(e&15)
    Ps[(u32)(wv*16 + (e >> 4))*296 + 272 + (e & 15)] = 0;
  }
  // ---- PV: O[16q][64d] = P[16][288] @ V[288][64]; K-loop 9, n-tiles 4 ----
  f32x4 o_[4];
  #pragma unroll
  for (int n = 0; n < 4; n++) o_[n] = (f32x4){0.f,0.f,0.f,0.f};
  #pragma unroll
  for (int ks = 0; ks < 9; ks++){
    const bf16x8 ap = *reinterpret_cast<const bf16x8*>(&Ps[(u32)(wv*16 + c16)*296 + ko*8 + ks*32]);
    #pragma unroll
    for (int n = 0; n < 4; n++){
      const bf16x8 bv = *reinterpret_cast<const bf16x8*>(&Vt[(u32)(n*16 + c16)*296 + ko*8 + ks*32]);
      o_[n] = __builtin_amdgcn_mfma_f32_16x16x32_bf16(ap, bv, o_[n], 0, 0, 0);
    }
  }
  // ---- epilogue: divide by rowsum, store bf16 ----
  #pragma unroll
  for (int jr = 0; jr < 4; jr++){
    const int r = wv*16 + ko*4 + jr;
    const float rs = 1.f / rsum[r];
    #pragma unroll
    for (int n = 0; n < 4; n++)
      ob[(size_t)(q0 + r)*DM + h*DHD + n*16 + c16] = f2bf(o_[n][jr] * rs);
  }
}

// ---------------- launch ----------------
extern "C" void kernel_launch(void* const* d_in, const int* in_sizes, int n_in,
                              void* d_out, int out_size, void* d_ws, size_t ws_size,
                              hipStream_t stream)
{
  (void)in_sizes; (void)n_in; (void)out_size; (void)ws_size;
  const int*   tokens   = (const int*)  d_in[0];
  const float* tok_emb  = (const float*)d_in[1];
  const float* gpos_emb = (const float*)d_in[2];
  const float* g_norm_w = (const float*)d_in[3];
  const float* g_norm_b = (const float*)d_in[4];
  const float* g_Wq     = (const float*)d_in[5];
  const float* g_Wkv    = (const float*)d_in[6];
  const float* g_Wo     = (const float*)d_in[7];
  const float* g_bo     = (const float*)d_in[8];
  const float* gffnw    = (const float*)d_in[9];
  const float* gffnb    = (const float*)d_in[10];
  const float* gff_W1   = (const float*)d_in[11];
  const float* gff_b1   = (const float*)d_in[12];
  const float* gff_W2   = (const float*)d_in[13];
  const float* gff_b2   = (const float*)d_in[14];
  const float* la_nw    = (const float*)d_in[15];
  const float* la_nb    = (const float*)d_in[16];
  const float* la_Wq    = (const float*)d_in[17];
  const float* la_Wkv   = (const float*)d_in[18];
  const float* la_Wo    = (const float*)d_in[19];
  const float* la_bo    = (const float*)d_in[20];
  const float* lff_nw   = (const float*)d_in[21];
  const float* lff_nb   = (const float*)d_in[22];
  const float* lff_W1   = (const float*)d_in[23];
  const float* lff_b1   = (const float*)d_in[24];
  const float* lff_W2   = (const float*)d_in[25];
  const float* lff_b2   = (const float*)d_in[26];
  const float* out_nw   = (const float*)d_in[27];
  const float* out_nb   = (const float*)d_in[28];
  const float* out_W    = (const float*)d_in[29];
  const float* out_b    = (const float*)d_in[30];
  float* O = (float*)d_out;

  float* ws = (float*)d_ws;
  float* x    = ws;                    // [2048,512] fp32 residual
  float* qb   = x + 1048576;           // [2048,512] q fp32 (qb..kb also = kvx [2048,1024])
  float* kb   = qb + 1048576;          // [2048,512] k fp32
  float* g    = kb + 1048576;          // [16,512]
  float* gn   = g + 8192;
  float* gq   = gn + 8192;
  float* gao  = gq + 8192;
  float* gkvg = gao + 8192;            // [16,1024]
  float* gh1  = gkvg + 16384;          // [16,2048]
  float* gkvl = gh1 + 32768;           // [15,1024]
  float* ct   = gkvl + 15360;          // [2048,32]
  float* st   = ct + 65536;
  u16* xb     = (u16*)(st + 65536);    // [2048,512] bf16 residual copy
  u16* xnb    = xb + 1048576;          // [2048,512] bf16 LN out
  u16* aob    = xnb + 1048576;         // [2048,512] bf16 attn out
  u16* h1b    = aob + 1048576;         // [2048,2048] bf16 FF hidden
  u16* Wt_voc = h1b + 4194304;         // [32000,512]
  u16* Wt_gkv = Wt_voc + 16384000;     // [1024,512]
  u16* Wt_ff1 = Wt_gkv + 524288;       // 2 x [2048,512]
  u16* Wt_ff2 = Wt_ff1 + 2097152;      // 2 x [512,2048]
  u16* Wt_q   = Wt_ff2 + 2097152;      // 2 x [512,512]
  u16* Wt_k   = Wt_q + 524288;         // 2 x [512,512] (K-half of la_Wkv)
  u16* Wt_o   = Wt_k + 524288;         // 2 x [512,512]
  // split-K partials (<=1MB) alias h1b (only live ff1->ff2 inside local FFN)
  float* P    = (float*)h1b;

  // ---- weight transpose+convert pre-pass (inputs only; graph-safe) ----
  k_wcvt<<<dim3(VOC/32, 16), 256, 0, stream>>>(out_W, VOC, 0, Wt_voc, DM);
  k_wcvt<<<dim3(32, 16),     256, 0, stream>>>(g_Wkv, 1024, 0, Wt_gkv, DM);
  for (int l=0;l<NDEPTH;l++){
    k_wcvt<<<dim3(64, 16), 256, 0, stream>>>(lff_W1 + (size_t)l*DM*FFD, FFD, 0, Wt_ff1 + (size_t)l*1048576, DM);
    k_wcvt<<<dim3(16, 64), 256, 0, stream>>>(lff_W2 + (size_t)l*FFD*DM, DM, 0, Wt_ff2 + (size_t)l*1048576, FFD);
    k_wcvt<<<dim3(16, 16), 256, 0, stream>>>(la_Wq  + (size_t)l*DM*DM, DM, 0, Wt_q + (size_t)l*262144, DM);
    k_wcvt<<<dim3(16, 16), 256, 0, stream>>>(la_Wkv + (size_t)l*DM*1024, 1024, 0, Wt_k + (size_t)l*262144, DM);
    k_wcvt<<<dim3(16, 16), 256, 0, stream>>>(la_Wo  + (size_t)l*DM*DM, DM, 0, Wt_o + (size_t)l*262144, DM);
  }

  k_embed<<<N_TOK*DM/256, 256, 0, stream>>>(tokens, tok_emb, x, xb);
  k_pool <<<NW*DM/256,   256, 0, stream>>>(x, gpos_emb, g);
  k_rotab<<<N_TOK*32/256,256, 0, stream>>>(ct, st);

  for (int l=0;l<NDEPTH;l++){
    // --- global-token transformer (weights shared across layers, fp32 split-K path) ---
    k_ln<false><<<NW,256,0,stream>>>(g, gn, nullptr, g_norm_w, g_norm_b);
    k_psum<<<dim3(4,8),256,0,stream>>>(gn, DM, g_Wkv, 1024, P, 1024, NW);
    k_red<false,false,false><<<64,256,0,stream>>>(P, 1024, 8, NW, gkvg, 1024, nullptr);
    k_psum<<<dim3(2,8),256,0,stream>>>(gn, DM, g_Wq, 512, P, 512, NW);
    k_red<false,false,false><<<32,256,0,stream>>>(P, 512, 8, NW, gq, 512, nullptr);
    // kvx = x @ g_Wkv (bf16 MFMA)
    k_mgemm<64,128,false,false,false,false,true><<<dim3(8,32),256,0,stream>>>(xb, DM, Wt_gkv, qb, 1024, nullptr, 0, nullptr, DM);
    k_gattn<<<NW*NH,64,0,stream>>>(gq, gkvg, qb, gao);
    k_psum<<<dim3(2,8),256,0,stream>>>(gao, DM, g_Wo, DM, P, 512, NW);
    k_red<true,true,false><<<32,256,0,stream>>>(P, 512, 8, NW, g, DM, g_bo);
    k_ln<false><<<NW,256,0,stream>>>(g, gn, nullptr, gffnw, gffnb);
    k_psum<<<dim3(8,8),256,0,stream>>>(gn, DM, gff_W1, FFD, P, FFD, NW);
    k_red<true,false,true><<<128,256,0,stream>>>(P, FFD, 8, NW, gh1, FFD, gff_b1);
    k_psum<<<dim3(2,32),256,0,stream>>>(gh1, FFD, gff_W2, DM, P, 512, NW);
    k_red<true,true,false><<<32,256,0,stream>>>(P, 512, 32, NW, g, DM, gff_b2);
    // --- local windowed attention ---
    k_psum<<<dim3(4,8),256,0,stream>>>(g, DM, la_Wkv + (size_t)l*DM*1024, 1024, P, 1024, 15);
    k_red<false,false,false><<<64,256,0,stream>>>(P, 1024, 8, 15, gkvl, 1024, nullptr);
    k_ln<true><<<N_TOK,256,0,stream>>>(x, nullptr, xnb, la_nw + l*DM, la_nb + l*DM);
    k_mgemm<64,64,false,false,false,false,true><<<dim3(8,32),256,0,stream>>>(xnb, DM, Wt_q + (size_t)l*262144, qb, DM, nullptr, 0, nullptr, DM);
    // only the K half of la_Wkv is live (reference bug: windowed V == windowed K)
    k_mgemm<64,64,false,false,false,false,true><<<dim3(8,32),256,0,stream>>>(xnb, DM, Wt_k + (size_t)l*262144, kb, DM, nullptr, 0, nullptr, DM);
    k_rope<<<N_TOK*NH*32/256,256,0,stream>>>(qb, kb, ct, st);
    k_lattn_m<<<NW*NH*2,256,0,stream>>>(qb, kb, gkvl, aob);
    k_mgemm<64,64,true,true,false,true,true><<<dim3(8,32),256,0,stream>>>(aob, DM, Wt_o + (size_t)l*262144, x, DM, xb, DM, la_bo + l*DM, DM);
    // --- local FFN ---
    k_ln<true><<<N_TOK,256,0,stream>>>(x, nullptr, xnb, lff_nw + l*DM, lff_nb + l*DM);
    k_mgemm<128,128,true,false,true,true,false><<<dim3(16,16),256,0,stream>>>(xnb, DM, Wt_ff1 + (size_t)l*1048576, nullptr, 0, h1b, FFD, lff_b1 + l*FFD, DM);
    k_mgemm<64,64,true,true,false,true,true><<<dim3(8,32),256,0,stream>>>(h1b, FFD, Wt_ff2 + (size_t)l*1048576, x, DM, xb, DM, lff_b2 + l*DM, FFD);
  }
  // --- output head (bf16 MFMA) ---
  k_ln<true><<<N_TOK,256,0,stream>>>(x, nullptr, xnb, out_nw, out_nb);
  k_mgemm<128,128,true,false,false,false,true><<<dim3(VOC/128,16),256,0,stream>>>(xnb, DM, Wt_voc, O, VOC, nullptr, 0, out_b, DM);
}